// Round 9
// baseline (823.690 us; speedup 1.0000x reference)
//
#include <hip/hip_runtime.h>
#include <hip/hip_bf16.h>

#define B_ 4
#define N_ 8192
#define D_ 512
#define H_ 8
#define DH_ 64
#define M_ 256
#define LCH 32
#define KER_ 33
#define NSPLIT 16
#define CS (N_/NSPLIT)   // 512 cols per split chunk

typedef __hip_bfloat16 bf16;
typedef __attribute__((ext_vector_type(8))) short short8;
typedef __attribute__((ext_vector_type(4))) short short4v;
typedef __attribute__((ext_vector_type(4))) float f32x4;

__device__ __forceinline__ float bf2f(bf16 h){ return __bfloat162float(h); }
__device__ __forceinline__ bf16 f2bf(float f){ return __float2bfloat16(f); }
__device__ __forceinline__ f32x4 mfma16(short8 a, short8 b, f32x4 c){
  return __builtin_amdgcn_mfma_f32_16x16x32_bf16(a, b, c, 0, 0, 0);
}

// ---------------- LayerNorm: x (b,n,512) fp32 -> xn bf16 ----------------
__global__ __launch_bounds__(256) void k_layernorm(const float* __restrict__ x,
    const float* __restrict__ gamma, const float* __restrict__ beta,
    bf16* __restrict__ xn){
  int row = blockIdx.x;
  const float* xr = x + (size_t)row * D_;
  bf16* o = xn + (size_t)row * D_;
  int t = threadIdx.x;
  float v0 = xr[t], v1 = xr[t+256];
  float s = v0+v1, ss = v0*v0 + v1*v1;
  __shared__ float sh[8];
  for (int off=32; off; off>>=1){ s += __shfl_xor(s,off); ss += __shfl_xor(ss,off); }
  int lane = t&63, wid = t>>6;
  if (lane==0){ sh[wid] = s; sh[wid+4] = ss; }
  __syncthreads();
  float S  = sh[0]+sh[1]+sh[2]+sh[3];
  float SS = sh[4]+sh[5]+sh[6]+sh[7];
  float mu = S*(1.f/D_);
  float var = SS*(1.f/D_) - mu*mu;
  float rs = rsqrtf(var + 1e-5f);
  o[t]     = f2bf((v0-mu)*rs*gamma[t]     + beta[t]);
  o[t+256] = f2bf((v1-mu)*rs*gamma[t+256] + beta[t+256]);
}

// ---------------- W transpose+convert: W (RxC fp32) -> WT (CxR bf16) ----------------
__global__ __launch_bounds__(256) void k_wt(const float* __restrict__ W, bf16* __restrict__ WT,
    int R, int C){
  int c0 = blockIdx.x*64, r0 = blockIdx.y*64;
  __shared__ float tile[64][65];
  int t = threadIdx.x;
  for (int i=t;i<4096;i+=256){ int r=i>>6, c=i&63; tile[r][c] = W[(size_t)(r0+r)*C + c0+c]; }
  __syncthreads();
  for (int i=t;i<512;i+=256){
    int c=i>>3, rg=i&7;
    short8 o;
    #pragma unroll
    for (int j=0;j<8;j++) ((bf16*)&o)[j] = f2bf(tile[rg*8+j][c]);
    *(short8*)&WT[(size_t)(c0+c)*R + r0 + rg*8] = o;
  }
}

// ---------------- QKV GEMM (MFMA, 128x256 tile, LDS-transposed full-line epilogue) ----------------
// XCD-chunked swizzle (round 8: FETCH 107->34.6MB, the ideal single A pass). Fuses landmark
// means (parts 0/1) and v->vT transpose (part 2). Round-9 fix: vT emitted via a SECOND ebuf
// pass filled TRANSPOSED from acc registers (8B ds_writes, 2-way bank spread = free) instead
// of the column-gather (272B-stride, 8-way conflict: 13M conflicts, +26us in round 8).
__global__ __launch_bounds__(256, 2) void k_mm_qkv4(const bf16* __restrict__ A, const bf16* __restrict__ WT,
    bf16* __restrict__ qbuf, bf16* __restrict__ kbuf, bf16* __restrict__ vbuf,
    bf16* __restrict__ vT, bf16* __restrict__ qlb, bf16* __restrict__ klb){
  __shared__ __align__(16) bf16 smem[3*128*72];
  bf16 (*As)[72]  = (bf16(*)[72])smem;
  bf16 (*Bs0)[72] = (bf16(*)[72])(smem + 128*72);
  bf16 (*Bs1)[72] = (bf16(*)[72])(smem + 2*128*72);
  bf16 (*ebuf)[136] = (bf16(*)[136])smem;   // epilogue reuse
  int t = threadIdx.x;
  int w = t>>6, lane = t&63, qd = lane>>4, n = lane&15;
  int wm = w>>1, wn = w&1;
  int bid = blockIdx.x;                 // 0..1535
  int xcd = bid & 7, pos = bid >> 3;
  int tid = xcd*192 + pos;              // contiguous tile range per XCD
  int cx = tid % 6, ry = tid / 6;       // 6 col-tiles of one row-panel consecutive
  int r0 = ry*128, c0 = cx*256;
  f32x4 acc[2][4][4];
  #pragma unroll
  for (int cb=0;cb<2;cb++)
    #pragma unroll
    for (int i=0;i<4;i++)
      #pragma unroll
      for (int j=0;j<4;j++) acc[cb][i][j] = (f32x4){0.f,0.f,0.f,0.f};
  int srow = t>>3, skc = t&7;
  for (int k0=0; k0<512; k0+=64){
    #pragma unroll
    for (int ch=0; ch<4; ch++){
      int m = ch*32 + srow;
      *(short8*)&As[m][skc*8]  = *(const short8*)&A [(size_t)(r0+m)*512 + k0 + skc*8];
      *(short8*)&Bs0[m][skc*8] = *(const short8*)&WT[(size_t)(c0+m)*512 + k0 + skc*8];
      *(short8*)&Bs1[m][skc*8] = *(const short8*)&WT[(size_t)(c0+128+m)*512 + k0 + skc*8];
    }
    __syncthreads();
    #pragma unroll
    for (int ksub=0; ksub<2; ksub++){
      short8 af[4];
      #pragma unroll
      for (int i=0;i<4;i++) af[i] = *(const short8*)&As[wm*64+i*16+n][ksub*32+qd*8];
      #pragma unroll
      for (int cb=0; cb<2; cb++){
        bf16 (*Bsc)[72] = cb ? Bs1 : Bs0;
        short8 bfr[4];
        #pragma unroll
        for (int j=0;j<4;j++) bfr[j] = *(const short8*)&Bsc[wn*64+j*16+n][ksub*32+qd*8];
        #pragma unroll
        for (int i=0;i<4;i++)
          #pragma unroll
          for (int j=0;j<4;j++) acc[cb][i][j] = mfma16(af[i], bfr[j], acc[cb][i][j]);
      }
    }
    __syncthreads();
  }
  int part = c0 >> 9;   // uniform per block
  bf16* dst = (part==0)? qbuf : (part==1)? kbuf : vbuf;
  float scale = (part==0)? 0.125f : 1.f;
  int b = r0 >> 13, nn = r0 & 8191;
  #pragma unroll
  for (int cb=0; cb<2; cb++){
    __syncthreads();
    #pragma unroll
    for (int i=0;i<4;i++)
      #pragma unroll
      for (int j=0;j<4;j++)
        #pragma unroll
        for (int rg=0; rg<4; rg++)
          ebuf[wm*64+i*16+qd*4+rg][wn*64+j*16+n] = f2bf(acc[cb][i][j][rg]*scale);
    __syncthreads();
    #pragma unroll
    for (int rep=0; rep<8; rep++){
      int unit = rep*256 + t;
      int row = unit >> 4, ch = unit & 15;
      int col = c0 + cb*128 + ch*8;
      int cc = col & 511, h = cc>>6, dh = cc&63;
      *(short8*)&dst[(((size_t)(b*H_+h))*N_ + nn + row)*DH_ + dh] = *(const short8*)&ebuf[row][ch*8];
    }
    if (part < 2){
      bf16* lt = (part==0) ? qlb : klb;
      #pragma unroll
      for (int rep=0; rep<2; rep++){
        int oi = rep*256 + t;          // 0..511: chunk(4) x col(128)
        int chunk = oi >> 7, col = oi & 127;
        float sum = 0.f;
        #pragma unroll
        for (int rr=0; rr<32; rr++) sum += bf2f(ebuf[chunk*32+rr][col]);
        int m = (nn >> 5) + chunk;
        int cc = (c0 + cb*128 + col) & 511;
        int h = cc >> 6, dh = cc & 63;
        lt[(((size_t)(b*H_+h))*M_ + m)*DH_ + dh] = f2bf(sum * (1.f/LCH));
      }
    } else {
      // pass B: refill ebuf TRANSPOSED from acc (ebuf[col][row]); thread's 4 rg = 4
      // consecutive rows = one 8B ds_write. Then vT rows are contiguous full-line stores.
      __syncthreads();
      #pragma unroll
      for (int i=0;i<4;i++)
        #pragma unroll
        for (int j=0;j<4;j++){
          short4v tv;
          #pragma unroll
          for (int rg=0; rg<4; rg++) ((bf16*)&tv)[rg] = f2bf(acc[cb][i][j][rg]);
          *(short4v*)&ebuf[wn*64+j*16+n][wm*64+i*16+qd*4] = tv;
        }
      __syncthreads();
      #pragma unroll
      for (int rep=0; rep<8; rep++){
        int unit = rep*256 + t;        // col(128) x ch(16)
        int col = unit >> 4, ch = unit & 15;
        int cc = (c0 + cb*128 + col) & 511;
        int h = cc >> 6, dh = cc & 63;
        *(short8*)&vT[(((size_t)(b*H_+h))*DH_ + dh)*N_ + nn + ch*8] = *(const short8*)&ebuf[col][ch*8];
      }
    }
  }
}

// ---------------- attn2 = softmax(q_l @ k_l^T) rows (fp32 + bf16 out) ----------------
__global__ __launch_bounds__(256) void k_attn2(const bf16* __restrict__ ql, const bf16* __restrict__ kl,
    float* __restrict__ A2, bf16* __restrict__ A2b){
  int bhm = blockIdx.x;
  int bh = bhm >> 8, m = bhm & 255;
  int t = threadIdx.x;
  __shared__ float qrow[64];
  __shared__ float sh[4];
  if (t < 64) qrow[t] = bf2f(ql[((size_t)bh*M_ + m)*DH_ + t]);
  __syncthreads();
  const bf16* krow = kl + ((size_t)bh*M_ + t)*DH_;
  float s = 0.f;
  #pragma unroll
  for (int i=0;i<64;i++) s += qrow[i]*bf2f(krow[i]);
  float mx = s;
  for (int off=32; off; off>>=1) mx = fmaxf(mx, __shfl_xor(mx, off));
  if ((t&63)==0) sh[t>>6] = mx;
  __syncthreads();
  mx = fmaxf(fmaxf(sh[0],sh[1]), fmaxf(sh[2],sh[3]));
  float e = expf(s - mx);
  float sum = e;
  for (int off=32; off; off>>=1) sum += __shfl_xor(sum, off);
  __syncthreads();
  if ((t&63)==0) sh[t>>6] = sum;
  __syncthreads();
  sum = sh[0]+sh[1]+sh[2]+sh[3];
  float r = e/sum;
  A2[((size_t)bh*M_ + m)*M_ + t] = r;
  A2b[((size_t)bh*M_ + m)*M_ + t] = f2bf(r);
}

// ---------------- pinv init: Z = A^T / (max_rowsum * max_colsum), bf16 out ----------------
__global__ __launch_bounds__(256) void k_pinv_init(const float* __restrict__ A2, bf16* __restrict__ Z){
  int bh = blockIdx.x;
  int t = threadIdx.x;
  const float* Ab = A2 + (size_t)bh*M_*M_;
  bf16* Zb = Z + (size_t)bh*M_*M_;
  float cs=0.f, rsm=0.f;
  for (int r=0;r<M_;r++) cs += fabsf(Ab[(size_t)r*M_ + t]);
  for (int c=0;c<M_;c++) rsm += fabsf(Ab[(size_t)t*M_ + c]);
  __shared__ float sh[4];
  float v = cs;
  for (int off=32; off; off>>=1) v = fmaxf(v, __shfl_xor(v, off));
  if ((t&63)==0) sh[t>>6] = v;
  __syncthreads();
  float maxc = fmaxf(fmaxf(sh[0],sh[1]), fmaxf(sh[2],sh[3]));
  __syncthreads();
  v = rsm;
  for (int off=32; off; off>>=1) v = fmaxf(v, __shfl_xor(v, off));
  if ((t&63)==0) sh[t>>6] = v;
  __syncthreads();
  float maxr = fmaxf(fmaxf(sh[0],sh[1]), fmaxf(sh[2],sh[3]));
  float inv = 1.f/(maxr*maxc);
  for (int r=0;r<M_;r++) Zb[(size_t)r*M_ + t] = f2bf(Ab[(size_t)t*M_ + r]*inv);
}

// ---------------- pinv GEMM, pure bf16 (plain NS iterations) ----------------
__global__ __launch_bounds__(256) void k_gemm_pmb(bf16* __restrict__ C, const bf16* __restrict__ A,
    const bf16* __restrict__ Bm, float bDiag, int bNeg, float cDiag, int cNeg, float cScale){
  int bh = blockIdx.y;
  int tm = blockIdx.x >> 2, tn = blockIdx.x & 3;
  const bf16* Ab = A  + (size_t)bh*65536;
  const bf16* Bb = Bm + (size_t)bh*65536;
  bf16* Cb = C + (size_t)bh*65536;
  __shared__ __align__(16) bf16 Ah[64][72];
  __shared__ __align__(16) bf16 Bh[64][72];
  int t = threadIdx.x;
  int w = t>>6, lane = t&63, qd = lane>>4, n = lane&15;
  int wm = w>>1, wn = w&1;
  int r0 = tm*64, c0 = tn*64;
  f32x4 acc[2][2];
  #pragma unroll
  for (int i=0;i<2;i++)
    #pragma unroll
    for (int j=0;j<2;j++) acc[i][j] = (f32x4){0.f,0.f,0.f,0.f};
  int srow = t>>3, skc = t&7;
  for (int k0=0; k0<256; k0+=64){
    #pragma unroll
    for (int ch=0; ch<2; ch++){
      int m = ch*32 + srow;
      *(short8*)&Ah[m][skc*8] = *(const short8*)&Ab[(size_t)(r0+m)*256 + k0 + skc*8];
      short8 vb = *(const short8*)&Bb[(size_t)(k0+m)*256 + c0 + skc*8];
      int kr = k0 + m;
      if (bNeg){
        #pragma unroll
        for (int j=0;j<8;j++){
          float x = (kr == (c0 + skc*8 + j) ? bDiag : 0.f) - bf2f(((bf16*)&vb)[j]);
          Bh[skc*8+j][m] = f2bf(x);
        }
      } else {
        #pragma unroll
        for (int j=0;j<8;j++) Bh[skc*8+j][m] = ((bf16*)&vb)[j];
      }
    }
    __syncthreads();
    #pragma unroll
    for (int ksub=0; ksub<2; ksub++){
      short8 afh[2], bfh[2];
      #pragma unroll
      for (int i=0;i<2;i++) afh[i] = *(const short8*)&Ah[wm*32+i*16+n][ksub*32+qd*8];
      #pragma unroll
      for (int j=0;j<2;j++) bfh[j] = *(const short8*)&Bh[wn*32+j*16+n][ksub*32+qd*8];
      #pragma unroll
      for (int i=0;i<2;i++)
        #pragma unroll
        for (int j=0;j<2;j++) acc[i][j] = mfma16(afh[i], bfh[j], acc[i][j]);
    }
    __syncthreads();
  }
  #pragma unroll
  for (int i=0;i<2;i++){
    #pragma unroll
    for (int j=0;j<2;j++){
      int cidx = c0 + wn*32 + j*16 + n;
      #pragma unroll
      for (int rg=0; rg<4; rg++){
        int r = r0 + wm*32 + i*16 + qd*4 + rg;
        float r_ = acc[i][j][rg];
        if (cNeg) r_ = ((r==cidx)? cDiag : 0.f) - r_;
        Cb[(size_t)r*256 + cidx] = f2bf(r_*cScale);
      }
    }
  }
}

// ---------------- pinv GEMM fp32 (split precision; aBf/bBf: operand is bf16, lo=0) ----------------
// NOTE (round 4): do NOT fuse via cooperative grid.sync — device-scope fences defeat
// cross-XCD cache reuse (560MB HBM refetch, 23x slower). Small launches win.
__global__ __launch_bounds__(256) void k_gemm_pm(float* __restrict__ C, const void* __restrict__ Av,
    const void* __restrict__ Bv, float bDiag, int bNeg, float cDiag, int cNeg, float cScale,
    int aBf, int bBf){
  int bh = blockIdx.y;
  int tm = blockIdx.x >> 2, tn = blockIdx.x & 3;
  const float* Af = (const float*)Av; const bf16* A16 = (const bf16*)Av;
  const float* Bf = (const float*)Bv; const bf16* B16 = (const bf16*)Bv;
  float* Cb = C + (size_t)bh*65536;
  __shared__ __align__(16) bf16 Ah[64][72];
  __shared__ __align__(16) bf16 Al[64][72];
  __shared__ __align__(16) bf16 Bh[64][72];
  __shared__ __align__(16) bf16 Bl[64][72];
  int t = threadIdx.x;
  int w = t>>6, lane = t&63, qd = lane>>4, n = lane&15;
  int wm = w>>1, wn = w&1;
  int r0 = tm*64, c0 = tn*64;
  f32x4 acc[2][2];
  #pragma unroll
  for (int i=0;i<2;i++)
    #pragma unroll
    for (int j=0;j<2;j++) acc[i][j] = (f32x4){0.f,0.f,0.f,0.f};
  int srow = t>>3, skc = t&7;
  for (int k0=0; k0<256; k0+=64){
    #pragma unroll
    for (int ch=0; ch<2; ch++){
      int m = ch*32 + srow;
      if (aBf){
        *(short8*)&Ah[m][skc*8] = *(const short8*)&A16[(size_t)bh*65536 + (size_t)(r0+m)*256 + k0 + skc*8];
      } else {
        short8 vh, vl;
        const float* ap = &Af[(size_t)bh*65536 + (size_t)(r0+m)*256 + k0 + skc*8];
        #pragma unroll
        for (int j=0;j<8;j++){
          float x = ap[j];
          bf16 h = f2bf(x);
          ((bf16*)&vh)[j] = h;
          ((bf16*)&vl)[j] = f2bf(x - bf2f(h));
        }
        *(short8*)&Ah[m][skc*8] = vh;
        *(short8*)&Al[m][skc*8] = vl;
      }
      int kr = k0 + m;
      if (bBf){
        short8 vb = *(const short8*)&B16[(size_t)bh*65536 + (size_t)(k0+m)*256 + c0 + skc*8];
        #pragma unroll
        for (int j=0;j<8;j++) Bh[skc*8+j][m] = ((bf16*)&vb)[j];  // bBf only used with bNeg==0
      } else {
        const float* bp = &Bf[(size_t)bh*65536 + (size_t)(k0+m)*256 + c0 + skc*8];
        #pragma unroll
        for (int j=0;j<8;j++){
          float x = bp[j];
          if (bNeg) x = (kr == (c0 + skc*8 + j) ? bDiag : 0.f) - x;
          bf16 h = f2bf(x);
          Bh[skc*8+j][m] = h;
          Bl[skc*8+j][m] = f2bf(x - bf2f(h));
        }
      }
    }
    __syncthreads();
    #pragma unroll
    for (int ksub=0; ksub<2; ksub++){
      short8 afh[2], afl[2], bfh[2], bfl[2];
      #pragma unroll
      for (int i=0;i<2;i++){
        afh[i] = *(const short8*)&Ah[wm*32+i*16+n][ksub*32+qd*8];
        if (!aBf) afl[i] = *(const short8*)&Al[wm*32+i*16+n][ksub*32+qd*8];
      }
      #pragma unroll
      for (int j=0;j<2;j++){
        bfh[j] = *(const short8*)&Bh[wn*32+j*16+n][ksub*32+qd*8];
        if (!bBf) bfl[j] = *(const short8*)&Bl[wn*32+j*16+n][ksub*32+qd*8];
      }
      #pragma unroll
      for (int i=0;i<2;i++)
        #pragma unroll
        for (int j=0;j<2;j++){
          if (!aBf) acc[i][j] = mfma16(afl[i], bfh[j], acc[i][j]);
          if (!bBf) acc[i][j] = mfma16(afh[i], bfl[j], acc[i][j]);
          acc[i][j] = mfma16(afh[i], bfh[j], acc[i][j]);
        }
    }
    __syncthreads();
  }
  #pragma unroll
  for (int i=0;i<2;i++){
    #pragma unroll
    for (int j=0;j<2;j++){
      int cidx = c0 + wn*32 + j*16 + n;
      #pragma unroll
      for (int rg=0; rg<4; rg++){
        int r = r0 + wm*32 + i*16 + qd*4 + rg;
        float r_ = acc[i][j][rg];
        if (cNeg) r_ = ((r==cidx)? cDiag : 0.f) - r_;
        Cb[(size_t)r*256 + cidx] = r_*cScale;
      }
    }
  }
}

// ---------------- batched GEMM 256x64x256: z2T = (Z @ kv3)^T ----------------
__global__ __launch_bounds__(256) void k_gemm_z2(bf16* __restrict__ z2t, const float* __restrict__ A,
    const bf16* __restrict__ Bm){
  int bh = blockIdx.y;
  int tm = blockIdx.x;
  const float* Ab = A  + (size_t)bh*65536;
  const bf16* Bb = Bm + (size_t)bh*M_*DH_;
  __shared__ float As[16][68];
  __shared__ float Bs[16][64];
  int t = threadIdx.x, tx = t&15, ty = t>>4;
  int r0 = tm*64;
  float acc[4][4] = {};
  for (int k0=0;k0<256;k0+=16){
    for (int i=t;i<1024;i+=256){
      int m=i>>4, kq=i&15;
      As[kq][m] = Ab[(size_t)(r0+m)*256 + k0+kq];
      int nn=i&63, k2=i>>6;
      Bs[k2][nn] = bf2f(Bb[(size_t)(k0+k2)*64 + nn]);
    }
    __syncthreads();
    #pragma unroll
    for (int kq=0;kq<16;kq++){
      float a0[4], b0[4];
      #pragma unroll
      for (int i=0;i<4;i++) a0[i] = As[kq][ty*4+i];
      #pragma unroll
      for (int j=0;j<4;j++) b0[j] = Bs[kq][tx*4+j];
      #pragma unroll
      for (int i=0;i<4;i++)
        #pragma unroll
        for (int j=0;j<4;j++) acc[i][j] += a0[i]*b0[j];
    }
    __syncthreads();
  }
  #pragma unroll
  for (int i=0;i<4;i++){
    int r = r0+ty*4+i;
    #pragma unroll
    for (int j=0;j<4;j++)
      z2t[(size_t)bh*16384 + (size_t)(tx*4+j)*256 + r] = f2bf(acc[i][j]);
  }
}

// ---------------- attn3 flash, no-max softmax (|s| <= ~2: exp safe, identical after norm) ----------------
__global__ __launch_bounds__(256, 2) void k_flash_split(const bf16* __restrict__ Q,
    const bf16* __restrict__ K, const bf16* __restrict__ VT,
    float* __restrict__ OP, float* __restrict__ LP){
  int bh = blockIdx.y;
  int sp = blockIdx.x;
  int t = threadIdx.x, w = t>>6, lane = t&63, qd = lane>>4, n = lane&15;
  int r0 = w*64;
  const size_t Qoff = ((size_t)bh*M_ + r0)*DH_;
  const size_t Koff = ((size_t)bh*N_ + (size_t)sp*CS)*DH_;
  const size_t Voff = (size_t)bh*DH_*N_ + (size_t)sp*CS;
  __shared__ __align__(16) bf16 pbuf[4][4][16][72];
  short8 aq[4][2];
  #pragma unroll
  for (int rt=0; rt<4; rt++){
    aq[rt][0] = *(const short8*)&Q[Qoff + (size_t)(rt*16+n)*DH_ + qd*8];
    aq[rt][1] = *(const short8*)&Q[Qoff + (size_t)(rt*16+n)*DH_ + 32 + qd*8];
  }
  f32x4 o[4][4];
  float lrun[4][4];
  #pragma unroll
  for (int rt=0; rt<4; rt++){
    #pragma unroll
    for (int j=0;j<4;j++){ o[rt][j] = (f32x4){0.f,0.f,0.f,0.f}; lrun[rt][j] = 0.f; }
  }
  for (int tl=0; tl<CS/64; ++tl){
    const bf16* kp = K + Koff + (size_t)(tl*64)*DH_;
    short8 kb[4][2];
    #pragma unroll
    for (int cg=0; cg<4; cg++){
      kb[cg][0] = *(const short8*)&kp[(size_t)(cg*16+n)*DH_ + qd*8];
      kb[cg][1] = *(const short8*)&kp[(size_t)(cg*16+n)*DH_ + 32 + qd*8];
    }
    #pragma unroll
    for (int rt=0; rt<4; rt++){
      f32x4 s[4];
      #pragma unroll
      for (int cg=0; cg<4; cg++){
        f32x4 z = (f32x4){0.f,0.f,0.f,0.f};
        z = mfma16(aq[rt][0], kb[cg][0], z);
        z = mfma16(aq[rt][1], kb[cg][1], z);
        s[cg] = z;
      }
      #pragma unroll
      for (int rg=0; rg<4; rg++){
        float p0 = __expf(s[0][rg]), p1 = __expf(s[1][rg]);
        float p2 = __expf(s[2][rg]), p3 = __expf(s[3][rg]);
        float ts = p0+p1+p2+p3;
        ts += __shfl_xor(ts,1); ts += __shfl_xor(ts,2);
        ts += __shfl_xor(ts,4); ts += __shfl_xor(ts,8);
        lrun[rt][rg] += ts;
        pbuf[w][rt][qd*4+rg][n]    = f2bf(p0);
        pbuf[w][rt][qd*4+rg][16+n] = f2bf(p1);
        pbuf[w][rt][qd*4+rg][32+n] = f2bf(p2);
        pbuf[w][rt][qd*4+rg][48+n] = f2bf(p3);
      }
    }
    const bf16* vp = VT + Voff + tl*64 + qd*8;
    short8 vb[4][2];
    #pragma unroll
    for (int dg=0; dg<4; dg++){
      vb[dg][0] = *(const short8*)&vp[(size_t)(dg*16+n)*N_];
      vb[dg][1] = *(const short8*)&vp[(size_t)(dg*16+n)*N_ + 32];
    }
    #pragma unroll
    for (int rt=0; rt<4; rt++){
      short8 ap0 = *(const short8*)&pbuf[w][rt][n][qd*8];
      short8 ap1 = *(const short8*)&pbuf[w][rt][n][32+qd*8];
      #pragma unroll
      for (int dg=0; dg<4; dg++){
        o[rt][dg] = mfma16(ap0, vb[dg][0], o[rt][dg]);
        o[rt][dg] = mfma16(ap1, vb[dg][1], o[rt][dg]);
      }
    }
  }
  size_t base = ((size_t)sp*(B_*H_) + bh)*M_;
  #pragma unroll
  for (int rt=0; rt<4; rt++){
    #pragma unroll
    for (int rg=0; rg<4; rg++){
      int row = r0 + rt*16 + qd*4 + rg;
      if (n==0) LP[base+row] = lrun[rt][rg];
      #pragma unroll
      for (int dg=0; dg<4; dg++)
        OP[(base+row)*DH_ + dg*16 + n] = o[rt][dg][rg];
    }
  }
}

// ---------------- merge NSPLIT flash partials -> kv3 (plain sums, no m) ----------------
__global__ __launch_bounds__(256) void k_flash_merge(const float* __restrict__ OP,
    const float* __restrict__ LP, bf16* __restrict__ O){
  int bh = blockIdx.y;
  int r = blockIdx.x*4 + (threadIdx.x>>6);
  int dh = threadIdx.x & 63;
  float acc = 0.f, den = 0.f;
  for (int s=0; s<NSPLIT; s++){
    size_t base = ((size_t)s*(B_*H_) + bh)*M_ + r;
    den += LP[base];
    acc += OP[base*DH_ + dh];
  }
  O[((size_t)bh*M_ + r)*DH_ + dh] = f2bf(acc/den);
}

// ---------------- attn1 flash, no-max softmax, 4 waves x 4 rowtiles ----------------
__global__ __launch_bounds__(256, 2) void k_flash_w3(const bf16* __restrict__ Q,
    const bf16* __restrict__ K, const bf16* __restrict__ VT, bf16* __restrict__ O){
  int bh = blockIdx.y;
  int t = threadIdx.x, w = t>>6, lane = t&63, qd = lane>>4, n = lane&15;
  int r0 = blockIdx.x*256 + w*64;
  const size_t Qoff = ((size_t)bh*N_ + r0)*DH_;
  const size_t Koff = (size_t)bh*M_*DH_;
  const size_t Voff = (size_t)bh*DH_*M_;
  __shared__ __align__(16) bf16 pbuf[4][4][16][72];
  short8 aq[4][2];
  #pragma unroll
  for (int rt=0; rt<4; rt++){
    aq[rt][0] = *(const short8*)&Q[Qoff + (size_t)(rt*16+n)*DH_ + qd*8];
    aq[rt][1] = *(const short8*)&Q[Qoff + (size_t)(rt*16+n)*DH_ + 32 + qd*8];
  }
  f32x4 o[4][4];
  float lrun[4][4];
  #pragma unroll
  for (int rt=0; rt<4; rt++){
    #pragma unroll
    for (int j=0;j<4;j++){ o[rt][j] = (f32x4){0.f,0.f,0.f,0.f}; lrun[rt][j] = 0.f; }
  }
  #pragma unroll
  for (int tl=0; tl<4; ++tl){
    const bf16* kp = K + Koff + (size_t)(tl*64)*DH_;
    short8 kb[4][2];
    #pragma unroll
    for (int cg=0; cg<4; cg++){
      kb[cg][0] = *(const short8*)&kp[(size_t)(cg*16+n)*DH_ + qd*8];
      kb[cg][1] = *(const short8*)&kp[(size_t)(cg*16+n)*DH_ + 32 + qd*8];
    }
    #pragma unroll
    for (int rt=0; rt<4; rt++){
      f32x4 s[4];
      #pragma unroll
      for (int cg=0; cg<4; cg++){
        f32x4 z = (f32x4){0.f,0.f,0.f,0.f};
        z = mfma16(aq[rt][0], kb[cg][0], z);
        z = mfma16(aq[rt][1], kb[cg][1], z);
        s[cg] = z;
      }
      #pragma unroll
      for (int rg=0; rg<4; rg++){
        float p0 = __expf(s[0][rg]), p1 = __expf(s[1][rg]);
        float p2 = __expf(s[2][rg]), p3 = __expf(s[3][rg]);
        float ts = p0+p1+p2+p3;
        ts += __shfl_xor(ts,1); ts += __shfl_xor(ts,2);
        ts += __shfl_xor(ts,4); ts += __shfl_xor(ts,8);
        lrun[rt][rg] += ts;
        pbuf[w][rt][qd*4+rg][n]    = f2bf(p0);
        pbuf[w][rt][qd*4+rg][16+n] = f2bf(p1);
        pbuf[w][rt][qd*4+rg][32+n] = f2bf(p2);
        pbuf[w][rt][qd*4+rg][48+n] = f2bf(p3);
      }
    }
    const bf16* vp = VT + Voff + tl*64 + qd*8;
    short8 vb[4][2];
    #pragma unroll
    for (int dg=0; dg<4; dg++){
      vb[dg][0] = *(const short8*)&vp[(size_t)(dg*16+n)*M_];
      vb[dg][1] = *(const short8*)&vp[(size_t)(dg*16+n)*M_ + 32];
    }
    #pragma unroll
    for (int rt=0; rt<4; rt++){
      short8 ap0 = *(const short8*)&pbuf[w][rt][n][qd*8];
      short8 ap1 = *(const short8*)&pbuf[w][rt][n][32+qd*8];
      #pragma unroll
      for (int dg=0; dg<4; dg++){
        o[rt][dg] = mfma16(ap0, vb[dg][0], o[rt][dg]);
        o[rt][dg] = mfma16(ap1, vb[dg][1], o[rt][dg]);
      }
    }
  }
  #pragma unroll
  for (int rt=0; rt<4; rt++){
    #pragma unroll
    for (int rg=0; rg<4; rg++){
      float inv = 1.f/lrun[rt][rg];
      size_t rowoff = ((size_t)bh*N_ + r0 + rt*16 + qd*4 + rg)*DH_;
      #pragma unroll
      for (int dg=0; dg<4; dg++)
        O[rowoff + dg*16 + n] = f2bf(o[rt][dg][rg]*inv);
    }
  }
}

// ---------------- depthwise conv(KER=33), LDS-tiled, vectorized RMW into outh ----------------
#define CCH 256
__global__ __launch_bounds__(256) void k_conv_add(const bf16* __restrict__ v, const float* __restrict__ w,
    bf16* __restrict__ outh){
  int bh = blockIdx.y;
  int n0 = blockIdx.x * CCH;
  int h = bh & 7;
  __shared__ bf16 vs[CCH+32][72];
  __shared__ float wk[KER_];
  int t = threadIdx.x;
  if (t < KER_) wk[t] = w[h*KER_ + t];
  const bf16* vb = v + (size_t)bh*N_*DH_;
  for (int i=t; i<(CCH+32)*8; i+=256){
    int r = i>>3, cg = i&7;
    int nn = n0 - 16 + r;
    short8 val = {0,0,0,0,0,0,0,0};
    if (nn >= 0 && nn < N_) val = *(const short8*)&vb[(size_t)nn*DH_ + cg*8];
    *(short8*)&vs[r][cg*8] = val;
  }
  __syncthreads();
  int dhg = t & 7, rowg = t >> 3;
  bf16* ob = outh + ((size_t)bh*N_ + n0)*DH_;
  #pragma unroll
  for (int rr=0; rr<8; rr++){
    int lr = rowg*8 + rr;
    float acc[8] = {0.f,0.f,0.f,0.f,0.f,0.f,0.f,0.f};
    for (int tt=0; tt<KER_; tt++){
      short8 vv = *(const short8*)&vs[lr+tt][dhg*8];
      float wt = wk[tt];
      #pragma unroll
      for (int j=0;j<8;j++) acc[j] += wt * bf2f(((bf16*)&vv)[j]);
    }
    short8 o = *(short8*)&ob[(size_t)lr*DH_ + dhg*8];
    #pragma unroll
    for (int j=0;j<8;j++) ((bf16*)&o)[j] = f2bf(bf2f(((bf16*)&o)[j]) + acc[j]);
    *(short8*)&ob[(size_t)lr*DH_ + dhg*8] = o;
  }
}

// ---------------- final GEMM: out = x + gather(outh) @ WT2^T + b_out ----------------
// 1D grid 1024 with XCD-chunked swizzle (same A-panel locality fix as qkv4).
__global__ __launch_bounds__(256) void k_mm_out2(const bf16* __restrict__ Ahd, const bf16* __restrict__ WT2,
    const float* __restrict__ bias, const float* __restrict__ xin, float* __restrict__ out){
  __shared__ __align__(16) bf16 As[128][72];
  __shared__ __align__(16) bf16 Bs[128][72];
  int t = threadIdx.x;
  int w = t>>6, lane = t&63, qd = lane>>4, n = lane&15;
  int wm = w>>1, wn = w&1;
  int bid = blockIdx.x;                // 0..1023
  int xcd = bid & 7, pos = bid >> 3;
  int tid = xcd*128 + pos;
  int cx = tid & 3, ry = tid >> 2;
  int r0 = ry*128, c0 = cx*128;
  f32x4 acc[4][4];
  #pragma unroll
  for (int i=0;i<4;i++)
    #pragma unroll
    for (int j=0;j<4;j++) acc[i][j] = (f32x4){0.f,0.f,0.f,0.f};
  int srow = t>>3, skc = t&7;
  for (int k0=0; k0<512; k0+=64){
    int h = k0 >> 6;
    #pragma unroll
    for (int ch=0; ch<4; ch++){
      int m = ch*32 + srow;
      int r = r0 + m, b = r>>13, nn = r&8191;
      *(short8*)&As[m][skc*8] = *(const short8*)&Ahd[((size_t)(b*H_+h)*N_ + nn)*DH_ + skc*8];
      *(short8*)&Bs[m][skc*8] = *(const short8*)&WT2[(size_t)(c0+m)*512 + k0 + skc*8];
    }
    __syncthreads();
    #pragma unroll
    for (int ksub=0; ksub<2; ksub++){
      short8 af[4], bfr[4];
      #pragma unroll
      for (int i=0;i<4;i++) af[i]  = *(const short8*)&As[wm*64+i*16+n][ksub*32+qd*8];
      #pragma unroll
      for (int j=0;j<4;j++) bfr[j] = *(const short8*)&Bs[wn*64+j*16+n][ksub*32+qd*8];
      #pragma unroll
      for (int i=0;i<4;i++)
        #pragma unroll
        for (int j=0;j<4;j++) acc[i][j] = mfma16(af[i], bfr[j], acc[i][j]);
    }
    __syncthreads();
  }
  #pragma unroll
  for (int i=0;i<4;i++){
    #pragma unroll
    for (int rg=0; rg<4; rg++){
      int r = r0 + wm*64 + i*16 + qd*4 + rg;
      size_t base = (size_t)r*512;
      #pragma unroll
      for (int j=0;j<4;j++){
        int c = c0 + wn*64 + j*16 + n;
        out[base + c] = acc[i][j][rg] + bias[c] + xin[base + c];
      }
    }
  }
}

extern "C" void kernel_launch(void* const* d_in, const int* in_sizes, int n_in,
                              void* d_out, int out_size, void* d_ws, size_t ws_size,
                              hipStream_t stream) {
  const float* x     = (const float*)d_in[0];
  const float* gamma = (const float*)d_in[1];
  const float* beta  = (const float*)d_in[2];
  const float* wqkv  = (const float*)d_in[3];
  const float* resk  = (const float*)d_in[4];
  const float* wout  = (const float*)d_in[5];
  const float* bout  = (const float*)d_in[6];
  float* out = (float*)d_out;

  const size_t SL = (size_t)B_*H_*N_*DH_;
  const size_t SM = (size_t)B_*H_*M_*DH_;
  const size_t SP = (size_t)B_*H_*M_*M_;

  bf16* xn  = (bf16*)d_ws;     // reused as: flash partial OP, then pinv P1..P4, then outh
  bf16* q   = xn + SL;
  bf16* k   = q + SL;          // k region dead after flash_split -> holds bf16 pinv scratch
  bf16* v   = k + SL;
  bf16* vT  = v + SL;
  bf16* ql  = vT + SL;
  bf16* kl  = ql + SM;
  bf16* kv3 = kl + SM;
  bf16* z2T = kv3 + SM;
  float* A2 = (float*)(z2T + SM);
  bf16* WT  = (bf16*)(A2 + SP);       // 1536 x 512 bf16
  bf16* WT2 = WT + (size_t)1536*512;  // 512 x 512 bf16
  float* P1 = (float*)xn;             // pinv fp32 scratch aliases xn (4*SP*4B == SL*2B)
  float* P2 = P1 + SP;
  float* P3 = P2 + SP;
  float* P4 = P3 + SP;
  float* OPp = (float*)xn;            // flash partials alias xn (dead before pinv)
  float* LPp = (float*)z2T;           // and z2T (dead until gemm_z2)
  // bf16 pinv scratch in dead k region (6*SP*2B = 25.2MB <= 33.5MB)
  bf16* A2b = k;
  bf16* Zb0 = A2b + SP;
  bf16* Zb1 = Zb0 + SP;
  bf16* Pb  = Zb1 + SP;
  bf16* Tb  = Pb + SP;
  bf16* Ub  = Tb + SP;

  k_wt<<<dim3(24, 8), 256, 0, stream>>>(wqkv, WT, 512, 1536);
  k_wt<<<dim3(8, 8), 256, 0, stream>>>(wout, WT2, 512, 512);
  k_layernorm<<<B_*N_, 256, 0, stream>>>(x, gamma, beta, xn);
  k_mm_qkv4<<<1536, 256, 0, stream>>>(xn, WT, q, k, v, vT, ql, kl);

  // attn3 flash (split + merge) BEFORE pinv so partials use the dead xn/z2T regions
  k_flash_split<<<dim3(NSPLIT, B_*H_), 256, 0, stream>>>(ql, k, vT, OPp, LPp);
  k_flash_merge<<<dim3(M_/4, B_*H_), 256, 0, stream>>>(OPp, LPp, kv3);

  k_attn2<<<B_*H_*M_, 256, 0, stream>>>(ql, kl, A2, A2b);
  k_pinv_init<<<B_*H_, 256, 0, stream>>>(A2, Zb0);

  // NS iterations 0-4: pure bf16 (ops already bf16-rounded in plain mode; storage matches)
  bf16* Zbi = Zb0; bf16* Zbo = Zb1;
  for (int it=0; it<5; ++it){
    k_gemm_pmb<<<dim3(16,32), 256, 0, stream>>>(Pb,  A2b, Zbi, 0.f,0, 0.f,0, 1.f);   // P = A2@Z
    k_gemm_pmb<<<dim3(16,32), 256, 0, stream>>>(Tb,  Pb,  Pb,  7.f,1, 15.f,1, 1.f);  // S = 15I-P@(7I-P)
    k_gemm_pmb<<<dim3(16,32), 256, 0, stream>>>(Ub,  Pb,  Tb,  0.f,0, 13.f,1, 1.f);  // U = 13I-P@S
    k_gemm_pmb<<<dim3(16,32), 256, 0, stream>>>(Zbo, Zbi, Ub,  0.f,0, 0.f,0, 0.25f); // Zn = .25*Z@U
    bf16* tt = Zbi; Zbi = Zbo; Zbo = tt;
  }
  // NS iteration 5: split precision fp32 (bf16 operands where exact: lo=0)
  k_gemm_pm<<<dim3(16,32), 256, 0, stream>>>(P2, A2, Zbi, 0.f,0, 0.f,0, 1.f,  0,1); // P
  k_gemm_pm<<<dim3(16,32), 256, 0, stream>>>(P3, P2, P2,  7.f,1, 15.f,1, 1.f, 0,0); // S
  k_gemm_pm<<<dim3(16,32), 256, 0, stream>>>(P4, P2, P3,  0.f,0, 13.f,1, 1.f, 0,0); // U
  k_gemm_pm<<<dim3(16,32), 256, 0, stream>>>(P1, Zbi, P4, 0.f,0, 0.f,0, 0.25f,1,0); // Zn->P1

  k_gemm_z2<<<dim3(4, B_*H_), 256, 0, stream>>>(z2T, P1, kv3);
  k_flash_w3<<<dim3(N_/256, B_*H_), 256, 0, stream>>>(q, kl, z2T, xn);
  k_conv_add<<<dim3(N_/CCH, B_*H_), 256, 0, stream>>>(v, resk, xn);
  k_mm_out2<<<1024, 256, 0, stream>>>(xn, WT2, bout, x, out);
}

// Round 10
// 707.483 us; speedup vs baseline: 1.1643x; 1.1643x over previous
//
#include <hip/hip_runtime.h>
#include <hip/hip_bf16.h>

#define B_ 4
#define N_ 8192
#define D_ 512
#define H_ 8
#define DH_ 64
#define M_ 256
#define LCH 32
#define KER_ 33
#define NSPLIT 16
#define CS (N_/NSPLIT)   // 512 cols per split chunk

typedef __hip_bfloat16 bf16;
typedef __attribute__((ext_vector_type(8))) short short8;
typedef __attribute__((ext_vector_type(4))) short short4v;
typedef __attribute__((ext_vector_type(4))) float f32x4;

__device__ __forceinline__ float bf2f(bf16 h){ return __bfloat162float(h); }
__device__ __forceinline__ bf16 f2bf(float f){ return __float2bfloat16(f); }
__device__ __forceinline__ f32x4 mfma16(short8 a, short8 b, f32x4 c){
  return __builtin_amdgcn_mfma_f32_16x16x32_bf16(a, b, c, 0, 0, 0);
}

// ---------------- LayerNorm: x (b,n,512) fp32 -> xn bf16 ----------------
__global__ __launch_bounds__(256) void k_layernorm(const float* __restrict__ x,
    const float* __restrict__ gamma, const float* __restrict__ beta,
    bf16* __restrict__ xn){
  int row = blockIdx.x;
  const float* xr = x + (size_t)row * D_;
  bf16* o = xn + (size_t)row * D_;
  int t = threadIdx.x;
  float v0 = xr[t], v1 = xr[t+256];
  float s = v0+v1, ss = v0*v0 + v1*v1;
  __shared__ float sh[8];
  for (int off=32; off; off>>=1){ s += __shfl_xor(s,off); ss += __shfl_xor(ss,off); }
  int lane = t&63, wid = t>>6;
  if (lane==0){ sh[wid] = s; sh[wid+4] = ss; }
  __syncthreads();
  float S  = sh[0]+sh[1]+sh[2]+sh[3];
  float SS = sh[4]+sh[5]+sh[6]+sh[7];
  float mu = S*(1.f/D_);
  float var = SS*(1.f/D_) - mu*mu;
  float rs = rsqrtf(var + 1e-5f);
  o[t]     = f2bf((v0-mu)*rs*gamma[t]     + beta[t]);
  o[t+256] = f2bf((v1-mu)*rs*gamma[t+256] + beta[t+256]);
}

// ---------------- W transpose+convert: W (RxC fp32) -> WT (CxR bf16) ----------------
__global__ __launch_bounds__(256) void k_wt(const float* __restrict__ W, bf16* __restrict__ WT,
    int R, int C){
  int c0 = blockIdx.x*64, r0 = blockIdx.y*64;
  __shared__ float tile[64][65];
  int t = threadIdx.x;
  for (int i=t;i<4096;i+=256){ int r=i>>6, c=i&63; tile[r][c] = W[(size_t)(r0+r)*C + c0+c]; }
  __syncthreads();
  for (int i=t;i<512;i+=256){
    int c=i>>3, rg=i&7;
    short8 o;
    #pragma unroll
    for (int j=0;j<8;j++) ((bf16*)&o)[j] = f2bf(tile[rg*8+j][c]);
    *(short8*)&WT[(size_t)(c0+c)*R + r0 + rg*8] = o;
  }
}

// ---------------- QKV GEMM (MFMA, 128x256 tile, LDS-transposed full-line epilogue) ----------------
// 2D grid (6,256): XCD swizzle REVERTED (round 8/9: FETCH 107->35MB but time 76->100us —
// kernel is not BW-bound; swizzle's concurrency pattern hurt). Keeps pass-B transposed-ebuf
// vT write (round-9 fix for the 13M-conflict column gather) + fused landmark means.
__global__ __launch_bounds__(256, 2) void k_mm_qkv4(const bf16* __restrict__ A, const bf16* __restrict__ WT,
    bf16* __restrict__ qbuf, bf16* __restrict__ kbuf, bf16* __restrict__ vbuf,
    bf16* __restrict__ vT, bf16* __restrict__ qlb, bf16* __restrict__ klb){
  __shared__ __align__(16) bf16 smem[3*128*72];
  bf16 (*As)[72]  = (bf16(*)[72])smem;
  bf16 (*Bs0)[72] = (bf16(*)[72])(smem + 128*72);
  bf16 (*Bs1)[72] = (bf16(*)[72])(smem + 2*128*72);
  bf16 (*ebuf)[136] = (bf16(*)[136])smem;   // epilogue reuse
  int t = threadIdx.x;
  int w = t>>6, lane = t&63, qd = lane>>4, n = lane&15;
  int wm = w>>1, wn = w&1;
  int r0 = blockIdx.y*128, c0 = blockIdx.x*256;
  f32x4 acc[2][4][4];
  #pragma unroll
  for (int cb=0;cb<2;cb++)
    #pragma unroll
    for (int i=0;i<4;i++)
      #pragma unroll
      for (int j=0;j<4;j++) acc[cb][i][j] = (f32x4){0.f,0.f,0.f,0.f};
  int srow = t>>3, skc = t&7;
  for (int k0=0; k0<512; k0+=64){
    #pragma unroll
    for (int ch=0; ch<4; ch++){
      int m = ch*32 + srow;
      *(short8*)&As[m][skc*8]  = *(const short8*)&A [(size_t)(r0+m)*512 + k0 + skc*8];
      *(short8*)&Bs0[m][skc*8] = *(const short8*)&WT[(size_t)(c0+m)*512 + k0 + skc*8];
      *(short8*)&Bs1[m][skc*8] = *(const short8*)&WT[(size_t)(c0+128+m)*512 + k0 + skc*8];
    }
    __syncthreads();
    #pragma unroll
    for (int ksub=0; ksub<2; ksub++){
      short8 af[4];
      #pragma unroll
      for (int i=0;i<4;i++) af[i] = *(const short8*)&As[wm*64+i*16+n][ksub*32+qd*8];
      #pragma unroll
      for (int cb=0; cb<2; cb++){
        bf16 (*Bsc)[72] = cb ? Bs1 : Bs0;
        short8 bfr[4];
        #pragma unroll
        for (int j=0;j<4;j++) bfr[j] = *(const short8*)&Bsc[wn*64+j*16+n][ksub*32+qd*8];
        #pragma unroll
        for (int i=0;i<4;i++)
          #pragma unroll
          for (int j=0;j<4;j++) acc[cb][i][j] = mfma16(af[i], bfr[j], acc[cb][i][j]);
      }
    }
    __syncthreads();
  }
  int part = c0 >> 9;   // uniform per block
  bf16* dst = (part==0)? qbuf : (part==1)? kbuf : vbuf;
  float scale = (part==0)? 0.125f : 1.f;
  int b = r0 >> 13, nn = r0 & 8191;
  #pragma unroll
  for (int cb=0; cb<2; cb++){
    __syncthreads();
    #pragma unroll
    for (int i=0;i<4;i++)
      #pragma unroll
      for (int j=0;j<4;j++)
        #pragma unroll
        for (int rg=0; rg<4; rg++)
          ebuf[wm*64+i*16+qd*4+rg][wn*64+j*16+n] = f2bf(acc[cb][i][j][rg]*scale);
    __syncthreads();
    #pragma unroll
    for (int rep=0; rep<8; rep++){
      int unit = rep*256 + t;
      int row = unit >> 4, ch = unit & 15;
      int col = c0 + cb*128 + ch*8;
      int cc = col & 511, h = cc>>6, dh = cc&63;
      *(short8*)&dst[(((size_t)(b*H_+h))*N_ + nn + row)*DH_ + dh] = *(const short8*)&ebuf[row][ch*8];
    }
    if (part < 2){
      bf16* lt = (part==0) ? qlb : klb;
      #pragma unroll
      for (int rep=0; rep<2; rep++){
        int oi = rep*256 + t;          // 0..511: chunk(4) x col(128)
        int chunk = oi >> 7, col = oi & 127;
        float sum = 0.f;
        #pragma unroll
        for (int rr=0; rr<32; rr++) sum += bf2f(ebuf[chunk*32+rr][col]);
        int m = (nn >> 5) + chunk;
        int cc = (c0 + cb*128 + col) & 511;
        int h = cc >> 6, dh = cc & 63;
        lt[(((size_t)(b*H_+h))*M_ + m)*DH_ + dh] = f2bf(sum * (1.f/LCH));
      }
    } else {
      // pass B: refill ebuf TRANSPOSED from acc (ebuf[col][row]); thread's 4 rg = 4
      // consecutive rows = one 8B ds_write. Then vT rows are contiguous full-line stores.
      __syncthreads();
      #pragma unroll
      for (int i=0;i<4;i++)
        #pragma unroll
        for (int j=0;j<4;j++){
          short4v tv;
          #pragma unroll
          for (int rg=0; rg<4; rg++) ((bf16*)&tv)[rg] = f2bf(acc[cb][i][j][rg]);
          *(short4v*)&ebuf[wn*64+j*16+n][wm*64+i*16+qd*4] = tv;
        }
      __syncthreads();
      #pragma unroll
      for (int rep=0; rep<8; rep++){
        int unit = rep*256 + t;        // col(128) x ch(16)
        int col = unit >> 4, ch = unit & 15;
        int cc = (c0 + cb*128 + col) & 511;
        int h = cc >> 6, dh = cc & 63;
        *(short8*)&vT[(((size_t)(b*H_+h))*DH_ + dh)*N_ + nn + ch*8] = *(const short8*)&ebuf[col][ch*8];
      }
    }
  }
}

// ---------------- attn2 = softmax(q_l @ k_l^T) rows (fp32 + bf16 out) ----------------
__global__ __launch_bounds__(256) void k_attn2(const bf16* __restrict__ ql, const bf16* __restrict__ kl,
    float* __restrict__ A2, bf16* __restrict__ A2b){
  int bhm = blockIdx.x;
  int bh = bhm >> 8, m = bhm & 255;
  int t = threadIdx.x;
  __shared__ float qrow[64];
  __shared__ float sh[4];
  if (t < 64) qrow[t] = bf2f(ql[((size_t)bh*M_ + m)*DH_ + t]);
  __syncthreads();
  const bf16* krow = kl + ((size_t)bh*M_ + t)*DH_;
  float s = 0.f;
  #pragma unroll
  for (int i=0;i<64;i++) s += qrow[i]*bf2f(krow[i]);
  float mx = s;
  for (int off=32; off; off>>=1) mx = fmaxf(mx, __shfl_xor(mx, off));
  if ((t&63)==0) sh[t>>6] = mx;
  __syncthreads();
  mx = fmaxf(fmaxf(sh[0],sh[1]), fmaxf(sh[2],sh[3]));
  float e = expf(s - mx);
  float sum = e;
  for (int off=32; off; off>>=1) sum += __shfl_xor(sum, off);
  __syncthreads();
  if ((t&63)==0) sh[t>>6] = sum;
  __syncthreads();
  sum = sh[0]+sh[1]+sh[2]+sh[3];
  float r = e/sum;
  A2[((size_t)bh*M_ + m)*M_ + t] = r;
  A2b[((size_t)bh*M_ + m)*M_ + t] = f2bf(r);
}

// ---------------- pinv init: Z = A^T / (max_rowsum * max_colsum), bf16 out ----------------
__global__ __launch_bounds__(256) void k_pinv_init(const float* __restrict__ A2, bf16* __restrict__ Z){
  int bh = blockIdx.x;
  int t = threadIdx.x;
  const float* Ab = A2 + (size_t)bh*M_*M_;
  bf16* Zb = Z + (size_t)bh*M_*M_;
  float cs=0.f, rsm=0.f;
  for (int r=0;r<M_;r++) cs += fabsf(Ab[(size_t)r*M_ + t]);
  for (int c=0;c<M_;c++) rsm += fabsf(Ab[(size_t)t*M_ + c]);
  __shared__ float sh[4];
  float v = cs;
  for (int off=32; off; off>>=1) v = fmaxf(v, __shfl_xor(v, off));
  if ((t&63)==0) sh[t>>6] = v;
  __syncthreads();
  float maxc = fmaxf(fmaxf(sh[0],sh[1]), fmaxf(sh[2],sh[3]));
  __syncthreads();
  v = rsm;
  for (int off=32; off; off>>=1) v = fmaxf(v, __shfl_xor(v, off));
  if ((t&63)==0) sh[t>>6] = v;
  __syncthreads();
  float maxr = fmaxf(fmaxf(sh[0],sh[1]), fmaxf(sh[2],sh[3]));
  float inv = 1.f/(maxr*maxc);
  for (int r=0;r<M_;r++) Zb[(size_t)r*M_ + t] = f2bf(Ab[(size_t)t*M_ + r]*inv);
}

// ---------------- pinv GEMM, pure bf16 (plain NS iterations) ----------------
__global__ __launch_bounds__(256) void k_gemm_pmb(bf16* __restrict__ C, const bf16* __restrict__ A,
    const bf16* __restrict__ Bm, float bDiag, int bNeg, float cDiag, int cNeg, float cScale){
  int bh = blockIdx.y;
  int tm = blockIdx.x >> 2, tn = blockIdx.x & 3;
  const bf16* Ab = A  + (size_t)bh*65536;
  const bf16* Bb = Bm + (size_t)bh*65536;
  bf16* Cb = C + (size_t)bh*65536;
  __shared__ __align__(16) bf16 Ah[64][72];
  __shared__ __align__(16) bf16 Bh[64][72];
  int t = threadIdx.x;
  int w = t>>6, lane = t&63, qd = lane>>4, n = lane&15;
  int wm = w>>1, wn = w&1;
  int r0 = tm*64, c0 = tn*64;
  f32x4 acc[2][2];
  #pragma unroll
  for (int i=0;i<2;i++)
    #pragma unroll
    for (int j=0;j<2;j++) acc[i][j] = (f32x4){0.f,0.f,0.f,0.f};
  int srow = t>>3, skc = t&7;
  for (int k0=0; k0<256; k0+=64){
    #pragma unroll
    for (int ch=0; ch<2; ch++){
      int m = ch*32 + srow;
      *(short8*)&Ah[m][skc*8] = *(const short8*)&Ab[(size_t)(r0+m)*256 + k0 + skc*8];
      short8 vb = *(const short8*)&Bb[(size_t)(k0+m)*256 + c0 + skc*8];
      int kr = k0 + m;
      if (bNeg){
        #pragma unroll
        for (int j=0;j<8;j++){
          float x = (kr == (c0 + skc*8 + j) ? bDiag : 0.f) - bf2f(((bf16*)&vb)[j]);
          Bh[skc*8+j][m] = f2bf(x);
        }
      } else {
        #pragma unroll
        for (int j=0;j<8;j++) Bh[skc*8+j][m] = ((bf16*)&vb)[j];
      }
    }
    __syncthreads();
    #pragma unroll
    for (int ksub=0; ksub<2; ksub++){
      short8 afh[2], bfh[2];
      #pragma unroll
      for (int i=0;i<2;i++) afh[i] = *(const short8*)&Ah[wm*32+i*16+n][ksub*32+qd*8];
      #pragma unroll
      for (int j=0;j<2;j++) bfh[j] = *(const short8*)&Bh[wn*32+j*16+n][ksub*32+qd*8];
      #pragma unroll
      for (int i=0;i<2;i++)
        #pragma unroll
        for (int j=0;j<2;j++) acc[i][j] = mfma16(afh[i], bfh[j], acc[i][j]);
    }
    __syncthreads();
  }
  #pragma unroll
  for (int i=0;i<2;i++){
    #pragma unroll
    for (int j=0;j<2;j++){
      int cidx = c0 + wn*32 + j*16 + n;
      #pragma unroll
      for (int rg=0; rg<4; rg++){
        int r = r0 + wm*32 + i*16 + qd*4 + rg;
        float r_ = acc[i][j][rg];
        if (cNeg) r_ = ((r==cidx)? cDiag : 0.f) - r_;
        Cb[(size_t)r*256 + cidx] = f2bf(r_*cScale);
      }
    }
  }
}

// ---------------- pinv GEMM fp32 (split precision; aBf/bBf: operand is bf16, lo=0) ----------------
// NOTE (round 4): do NOT fuse via cooperative grid.sync — device-scope fences defeat
// cross-XCD cache reuse (560MB HBM refetch, 23x slower). Small launches win.
__global__ __launch_bounds__(256) void k_gemm_pm(float* __restrict__ C, const void* __restrict__ Av,
    const void* __restrict__ Bv, float bDiag, int bNeg, float cDiag, int cNeg, float cScale,
    int aBf, int bBf){
  int bh = blockIdx.y;
  int tm = blockIdx.x >> 2, tn = blockIdx.x & 3;
  const float* Af = (const float*)Av; const bf16* A16 = (const bf16*)Av;
  const float* Bf = (const float*)Bv; const bf16* B16 = (const bf16*)Bv;
  float* Cb = C + (size_t)bh*65536;
  __shared__ __align__(16) bf16 Ah[64][72];
  __shared__ __align__(16) bf16 Al[64][72];
  __shared__ __align__(16) bf16 Bh[64][72];
  __shared__ __align__(16) bf16 Bl[64][72];
  int t = threadIdx.x;
  int w = t>>6, lane = t&63, qd = lane>>4, n = lane&15;
  int wm = w>>1, wn = w&1;
  int r0 = tm*64, c0 = tn*64;
  f32x4 acc[2][2];
  #pragma unroll
  for (int i=0;i<2;i++)
    #pragma unroll
    for (int j=0;j<2;j++) acc[i][j] = (f32x4){0.f,0.f,0.f,0.f};
  int srow = t>>3, skc = t&7;
  for (int k0=0; k0<256; k0+=64){
    #pragma unroll
    for (int ch=0; ch<2; ch++){
      int m = ch*32 + srow;
      if (aBf){
        *(short8*)&Ah[m][skc*8] = *(const short8*)&A16[(size_t)bh*65536 + (size_t)(r0+m)*256 + k0 + skc*8];
      } else {
        short8 vh, vl;
        const float* ap = &Af[(size_t)bh*65536 + (size_t)(r0+m)*256 + k0 + skc*8];
        #pragma unroll
        for (int j=0;j<8;j++){
          float x = ap[j];
          bf16 h = f2bf(x);
          ((bf16*)&vh)[j] = h;
          ((bf16*)&vl)[j] = f2bf(x - bf2f(h));
        }
        *(short8*)&Ah[m][skc*8] = vh;
        *(short8*)&Al[m][skc*8] = vl;
      }
      int kr = k0 + m;
      if (bBf){
        short8 vb = *(const short8*)&B16[(size_t)bh*65536 + (size_t)(k0+m)*256 + c0 + skc*8];
        #pragma unroll
        for (int j=0;j<8;j++) Bh[skc*8+j][m] = ((bf16*)&vb)[j];  // bBf only used with bNeg==0
      } else {
        const float* bp = &Bf[(size_t)bh*65536 + (size_t)(k0+m)*256 + c0 + skc*8];
        #pragma unroll
        for (int j=0;j<8;j++){
          float x = bp[j];
          if (bNeg) x = (kr == (c0 + skc*8 + j) ? bDiag : 0.f) - x;
          bf16 h = f2bf(x);
          Bh[skc*8+j][m] = h;
          Bl[skc*8+j][m] = f2bf(x - bf2f(h));
        }
      }
    }
    __syncthreads();
    #pragma unroll
    for (int ksub=0; ksub<2; ksub++){
      short8 afh[2], afl[2], bfh[2], bfl[2];
      #pragma unroll
      for (int i=0;i<2;i++){
        afh[i] = *(const short8*)&Ah[wm*32+i*16+n][ksub*32+qd*8];
        if (!aBf) afl[i] = *(const short8*)&Al[wm*32+i*16+n][ksub*32+qd*8];
      }
      #pragma unroll
      for (int j=0;j<2;j++){
        bfh[j] = *(const short8*)&Bh[wn*32+j*16+n][ksub*32+qd*8];
        if (!bBf) bfl[j] = *(const short8*)&Bl[wn*32+j*16+n][ksub*32+qd*8];
      }
      #pragma unroll
      for (int i=0;i<2;i++)
        #pragma unroll
        for (int j=0;j<2;j++){
          if (!aBf) acc[i][j] = mfma16(afl[i], bfh[j], acc[i][j]);
          if (!bBf) acc[i][j] = mfma16(afh[i], bfl[j], acc[i][j]);
          acc[i][j] = mfma16(afh[i], bfh[j], acc[i][j]);
        }
    }
    __syncthreads();
  }
  #pragma unroll
  for (int i=0;i<2;i++){
    #pragma unroll
    for (int j=0;j<2;j++){
      int cidx = c0 + wn*32 + j*16 + n;
      #pragma unroll
      for (int rg=0; rg<4; rg++){
        int r = r0 + wm*32 + i*16 + qd*4 + rg;
        float r_ = acc[i][j][rg];
        if (cNeg) r_ = ((r==cidx)? cDiag : 0.f) - r_;
        Cb[(size_t)r*256 + cidx] = r_*cScale;
      }
    }
  }
}

// ---------------- batched GEMM 256x64x256: z2T = (Z @ kv3)^T ----------------
__global__ __launch_bounds__(256) void k_gemm_z2(bf16* __restrict__ z2t, const float* __restrict__ A,
    const bf16* __restrict__ Bm){
  int bh = blockIdx.y;
  int tm = blockIdx.x;
  const float* Ab = A  + (size_t)bh*65536;
  const bf16* Bb = Bm + (size_t)bh*M_*DH_;
  __shared__ float As[16][68];
  __shared__ float Bs[16][64];
  int t = threadIdx.x, tx = t&15, ty = t>>4;
  int r0 = tm*64;
  float acc[4][4] = {};
  for (int k0=0;k0<256;k0+=16){
    for (int i=t;i<1024;i+=256){
      int m=i>>4, kq=i&15;
      As[kq][m] = Ab[(size_t)(r0+m)*256 + k0+kq];
      int nn=i&63, k2=i>>6;
      Bs[k2][nn] = bf2f(Bb[(size_t)(k0+k2)*64 + nn]);
    }
    __syncthreads();
    #pragma unroll
    for (int kq=0;kq<16;kq++){
      float a0[4], b0[4];
      #pragma unroll
      for (int i=0;i<4;i++) a0[i] = As[kq][ty*4+i];
      #pragma unroll
      for (int j=0;j<4;j++) b0[j] = Bs[kq][tx*4+j];
      #pragma unroll
      for (int i=0;i<4;i++)
        #pragma unroll
        for (int j=0;j<4;j++) acc[i][j] += a0[i]*b0[j];
    }
    __syncthreads();
  }
  #pragma unroll
  for (int i=0;i<4;i++){
    int r = r0+ty*4+i;
    #pragma unroll
    for (int j=0;j<4;j++)
      z2t[(size_t)bh*16384 + (size_t)(tx*4+j)*256 + r] = f2bf(acc[i][j]);
  }
}

// ---------------- attn3 flash, no-max softmax (|s| <= ~2: exp safe, identical after norm) ----------------
__global__ __launch_bounds__(256, 2) void k_flash_split(const bf16* __restrict__ Q,
    const bf16* __restrict__ K, const bf16* __restrict__ VT,
    float* __restrict__ OP, float* __restrict__ LP){
  int bh = blockIdx.y;
  int sp = blockIdx.x;
  int t = threadIdx.x, w = t>>6, lane = t&63, qd = lane>>4, n = lane&15;
  int r0 = w*64;
  const size_t Qoff = ((size_t)bh*M_ + r0)*DH_;
  const size_t Koff = ((size_t)bh*N_ + (size_t)sp*CS)*DH_;
  const size_t Voff = (size_t)bh*DH_*N_ + (size_t)sp*CS;
  __shared__ __align__(16) bf16 pbuf[4][4][16][72];
  short8 aq[4][2];
  #pragma unroll
  for (int rt=0; rt<4; rt++){
    aq[rt][0] = *(const short8*)&Q[Qoff + (size_t)(rt*16+n)*DH_ + qd*8];
    aq[rt][1] = *(const short8*)&Q[Qoff + (size_t)(rt*16+n)*DH_ + 32 + qd*8];
  }
  f32x4 o[4][4];
  float lrun[4][4];
  #pragma unroll
  for (int rt=0; rt<4; rt++){
    #pragma unroll
    for (int j=0;j<4;j++){ o[rt][j] = (f32x4){0.f,0.f,0.f,0.f}; lrun[rt][j] = 0.f; }
  }
  for (int tl=0; tl<CS/64; ++tl){
    const bf16* kp = K + Koff + (size_t)(tl*64)*DH_;
    short8 kb[4][2];
    #pragma unroll
    for (int cg=0; cg<4; cg++){
      kb[cg][0] = *(const short8*)&kp[(size_t)(cg*16+n)*DH_ + qd*8];
      kb[cg][1] = *(const short8*)&kp[(size_t)(cg*16+n)*DH_ + 32 + qd*8];
    }
    #pragma unroll
    for (int rt=0; rt<4; rt++){
      f32x4 s[4];
      #pragma unroll
      for (int cg=0; cg<4; cg++){
        f32x4 z = (f32x4){0.f,0.f,0.f,0.f};
        z = mfma16(aq[rt][0], kb[cg][0], z);
        z = mfma16(aq[rt][1], kb[cg][1], z);
        s[cg] = z;
      }
      #pragma unroll
      for (int rg=0; rg<4; rg++){
        float p0 = __expf(s[0][rg]), p1 = __expf(s[1][rg]);
        float p2 = __expf(s[2][rg]), p3 = __expf(s[3][rg]);
        float ts = p0+p1+p2+p3;
        ts += __shfl_xor(ts,1); ts += __shfl_xor(ts,2);
        ts += __shfl_xor(ts,4); ts += __shfl_xor(ts,8);
        lrun[rt][rg] += ts;
        pbuf[w][rt][qd*4+rg][n]    = f2bf(p0);
        pbuf[w][rt][qd*4+rg][16+n] = f2bf(p1);
        pbuf[w][rt][qd*4+rg][32+n] = f2bf(p2);
        pbuf[w][rt][qd*4+rg][48+n] = f2bf(p3);
      }
    }
    const bf16* vp = VT + Voff + tl*64 + qd*8;
    short8 vb[4][2];
    #pragma unroll
    for (int dg=0; dg<4; dg++){
      vb[dg][0] = *(const short8*)&vp[(size_t)(dg*16+n)*N_];
      vb[dg][1] = *(const short8*)&vp[(size_t)(dg*16+n)*N_ + 32];
    }
    #pragma unroll
    for (int rt=0; rt<4; rt++){
      short8 ap0 = *(const short8*)&pbuf[w][rt][n][qd*8];
      short8 ap1 = *(const short8*)&pbuf[w][rt][n][32+qd*8];
      #pragma unroll
      for (int dg=0; dg<4; dg++){
        o[rt][dg] = mfma16(ap0, vb[dg][0], o[rt][dg]);
        o[rt][dg] = mfma16(ap1, vb[dg][1], o[rt][dg]);
      }
    }
  }
  size_t base = ((size_t)sp*(B_*H_) + bh)*M_;
  #pragma unroll
  for (int rt=0; rt<4; rt++){
    #pragma unroll
    for (int rg=0; rg<4; rg++){
      int row = r0 + rt*16 + qd*4 + rg;
      if (n==0) LP[base+row] = lrun[rt][rg];
      #pragma unroll
      for (int dg=0; dg<4; dg++)
        OP[(base+row)*DH_ + dg*16 + n] = o[rt][dg][rg];
    }
  }
}

// ---------------- merge NSPLIT flash partials -> kv3 (plain sums, no m) ----------------
__global__ __launch_bounds__(256) void k_flash_merge(const float* __restrict__ OP,
    const float* __restrict__ LP, bf16* __restrict__ O){
  int bh = blockIdx.y;
  int r = blockIdx.x*4 + (threadIdx.x>>6);
  int dh = threadIdx.x & 63;
  float acc = 0.f, den = 0.f;
  for (int s=0; s<NSPLIT; s++){
    size_t base = ((size_t)s*(B_*H_) + bh)*M_ + r;
    den += LP[base];
    acc += OP[base*DH_ + dh];
  }
  O[((size_t)bh*M_ + r)*DH_ + dh] = f2bf(acc/den);
}

// ---------------- attn1 flash, no-max softmax, 4 waves x 4 rowtiles ----------------
__global__ __launch_bounds__(256, 2) void k_flash_w3(const bf16* __restrict__ Q,
    const bf16* __restrict__ K, const bf16* __restrict__ VT, bf16* __restrict__ O){
  int bh = blockIdx.y;
  int t = threadIdx.x, w = t>>6, lane = t&63, qd = lane>>4, n = lane&15;
  int r0 = blockIdx.x*256 + w*64;
  const size_t Qoff = ((size_t)bh*N_ + r0)*DH_;
  const size_t Koff = (size_t)bh*M_*DH_;
  const size_t Voff = (size_t)bh*DH_*M_;
  __shared__ __align__(16) bf16 pbuf[4][4][16][72];
  short8 aq[4][2];
  #pragma unroll
  for (int rt=0; rt<4; rt++){
    aq[rt][0] = *(const short8*)&Q[Qoff + (size_t)(rt*16+n)*DH_ + qd*8];
    aq[rt][1] = *(const short8*)&Q[Qoff + (size_t)(rt*16+n)*DH_ + 32 + qd*8];
  }
  f32x4 o[4][4];
  float lrun[4][4];
  #pragma unroll
  for (int rt=0; rt<4; rt++){
    #pragma unroll
    for (int j=0;j<4;j++){ o[rt][j] = (f32x4){0.f,0.f,0.f,0.f}; lrun[rt][j] = 0.f; }
  }
  #pragma unroll
  for (int tl=0; tl<4; ++tl){
    const bf16* kp = K + Koff + (size_t)(tl*64)*DH_;
    short8 kb[4][2];
    #pragma unroll
    for (int cg=0; cg<4; cg++){
      kb[cg][0] = *(const short8*)&kp[(size_t)(cg*16+n)*DH_ + qd*8];
      kb[cg][1] = *(const short8*)&kp[(size_t)(cg*16+n)*DH_ + 32 + qd*8];
    }
    #pragma unroll
    for (int rt=0; rt<4; rt++){
      f32x4 s[4];
      #pragma unroll
      for (int cg=0; cg<4; cg++){
        f32x4 z = (f32x4){0.f,0.f,0.f,0.f};
        z = mfma16(aq[rt][0], kb[cg][0], z);
        z = mfma16(aq[rt][1], kb[cg][1], z);
        s[cg] = z;
      }
      #pragma unroll
      for (int rg=0; rg<4; rg++){
        float p0 = __expf(s[0][rg]), p1 = __expf(s[1][rg]);
        float p2 = __expf(s[2][rg]), p3 = __expf(s[3][rg]);
        float ts = p0+p1+p2+p3;
        ts += __shfl_xor(ts,1); ts += __shfl_xor(ts,2);
        ts += __shfl_xor(ts,4); ts += __shfl_xor(ts,8);
        lrun[rt][rg] += ts;
        pbuf[w][rt][qd*4+rg][n]    = f2bf(p0);
        pbuf[w][rt][qd*4+rg][16+n] = f2bf(p1);
        pbuf[w][rt][qd*4+rg][32+n] = f2bf(p2);
        pbuf[w][rt][qd*4+rg][48+n] = f2bf(p3);
      }
    }
    const bf16* vp = VT + Voff + tl*64 + qd*8;
    short8 vb[4][2];
    #pragma unroll
    for (int dg=0; dg<4; dg++){
      vb[dg][0] = *(const short8*)&vp[(size_t)(dg*16+n)*M_];
      vb[dg][1] = *(const short8*)&vp[(size_t)(dg*16+n)*M_ + 32];
    }
    #pragma unroll
    for (int rt=0; rt<4; rt++){
      short8 ap0 = *(const short8*)&pbuf[w][rt][n][qd*8];
      short8 ap1 = *(const short8*)&pbuf[w][rt][n][32+qd*8];
      #pragma unroll
      for (int dg=0; dg<4; dg++){
        o[rt][dg] = mfma16(ap0, vb[dg][0], o[rt][dg]);
        o[rt][dg] = mfma16(ap1, vb[dg][1], o[rt][dg]);
      }
    }
  }
  #pragma unroll
  for (int rt=0; rt<4; rt++){
    #pragma unroll
    for (int rg=0; rg<4; rg++){
      float inv = 1.f/lrun[rt][rg];
      size_t rowoff = ((size_t)bh*N_ + r0 + rt*16 + qd*4 + rg)*DH_;
      #pragma unroll
      for (int dg=0; dg<4; dg++)
        O[rowoff + dg*16 + n] = f2bf(o[rt][dg][rg]*inv);
    }
  }
}

// ---------------- depthwise conv(KER=33): CCH=128 (23KB LDS -> 4+ blocks/CU), prefetched RMW,
// tap loop unrolled x3. Round 9: 103us at Occ 27%/VALU 29% — latency-bound, not BW/compute. ----
#define CCH 128
__global__ __launch_bounds__(256, 4) void k_conv_add(const bf16* __restrict__ v, const float* __restrict__ w,
    bf16* __restrict__ outh){
  int bh = blockIdx.y;
  int n0 = blockIdx.x * CCH;
  int h = bh & 7;
  __shared__ bf16 vs[CCH+32][72];
  __shared__ float wk[KER_];
  int t = threadIdx.x;
  if (t < KER_) wk[t] = w[h*KER_ + t];
  const bf16* vb = v + (size_t)bh*N_*DH_;
  for (int i=t; i<(CCH+32)*8; i+=256){
    int r = i>>3, cg = i&7;
    int nn = n0 - 16 + r;
    short8 val = {0,0,0,0,0,0,0,0};
    if (nn >= 0 && nn < N_) val = *(const short8*)&vb[(size_t)nn*DH_ + cg*8];
    *(short8*)&vs[r][cg*8] = val;
  }
  __syncthreads();
  int dhg = t & 7, rowg = t >> 3;
  bf16* ob = outh + ((size_t)bh*N_ + n0)*DH_;
  #pragma unroll
  for (int rr=0; rr<4; rr++){
    int lr = rowg*4 + rr;
    short8 o = *(short8*)&ob[(size_t)lr*DH_ + dhg*8];   // issue RMW load before taps
    float acc[8] = {0.f,0.f,0.f,0.f,0.f,0.f,0.f,0.f};
    #pragma unroll 3
    for (int tt=0; tt<KER_; tt++){
      short8 vv = *(const short8*)&vs[lr+tt][dhg*8];
      float wt = wk[tt];
      #pragma unroll
      for (int j=0;j<8;j++) acc[j] += wt * bf2f(((bf16*)&vv)[j]);
    }
    #pragma unroll
    for (int j=0;j<8;j++) ((bf16*)&o)[j] = f2bf(bf2f(((bf16*)&o)[j]) + acc[j]);
    *(short8*)&ob[(size_t)lr*DH_ + dhg*8] = o;
  }
}

// ---------------- final GEMM: out = x + gather(outh) @ WT2^T + b_out ----------------
// 1D grid 1024 with XCD-chunked swizzle (kept: mm_out2 writes fp32 out, more BW-sensitive).
__global__ __launch_bounds__(256) void k_mm_out2(const bf16* __restrict__ Ahd, const bf16* __restrict__ WT2,
    const float* __restrict__ bias, const float* __restrict__ xin, float* __restrict__ out){
  __shared__ __align__(16) bf16 As[128][72];
  __shared__ __align__(16) bf16 Bs[128][72];
  int t = threadIdx.x;
  int w = t>>6, lane = t&63, qd = lane>>4, n = lane&15;
  int wm = w>>1, wn = w&1;
  int bid = blockIdx.x;                // 0..1023
  int xcd = bid & 7, pos = bid >> 3;
  int tid = xcd*128 + pos;
  int cx = tid & 3, ry = tid >> 2;
  int r0 = ry*128, c0 = cx*128;
  f32x4 acc[4][4];
  #pragma unroll
  for (int i=0;i<4;i++)
    #pragma unroll
    for (int j=0;j<4;j++) acc[i][j] = (f32x4){0.f,0.f,0.f,0.f};
  int srow = t>>3, skc = t&7;
  for (int k0=0; k0<512; k0+=64){
    int h = k0 >> 6;
    #pragma unroll
    for (int ch=0; ch<4; ch++){
      int m = ch*32 + srow;
      int r = r0 + m, b = r>>13, nn = r&8191;
      *(short8*)&As[m][skc*8] = *(const short8*)&Ahd[((size_t)(b*H_+h)*N_ + nn)*DH_ + skc*8];
      *(short8*)&Bs[m][skc*8] = *(const short8*)&WT2[(size_t)(c0+m)*512 + k0 + skc*8];
    }
    __syncthreads();
    #pragma unroll
    for (int ksub=0; ksub<2; ksub++){
      short8 af[4], bfr[4];
      #pragma unroll
      for (int i=0;i<4;i++) af[i]  = *(const short8*)&As[wm*64+i*16+n][ksub*32+qd*8];
      #pragma unroll
      for (int j=0;j<4;j++) bfr[j] = *(const short8*)&Bs[wn*64+j*16+n][ksub*32+qd*8];
      #pragma unroll
      for (int i=0;i<4;i++)
        #pragma unroll
        for (int j=0;j<4;j++) acc[i][j] = mfma16(af[i], bfr[j], acc[i][j]);
    }
    __syncthreads();
  }
  #pragma unroll
  for (int i=0;i<4;i++){
    #pragma unroll
    for (int rg=0; rg<4; rg++){
      int r = r0 + wm*64 + i*16 + qd*4 + rg;
      size_t base = (size_t)r*512;
      #pragma unroll
      for (int j=0;j<4;j++){
        int c = c0 + wn*64 + j*16 + n;
        out[base + c] = acc[i][j][rg] + bias[c] + xin[base + c];
      }
    }
  }
}

extern "C" void kernel_launch(void* const* d_in, const int* in_sizes, int n_in,
                              void* d_out, int out_size, void* d_ws, size_t ws_size,
                              hipStream_t stream) {
  const float* x     = (const float*)d_in[0];
  const float* gamma = (const float*)d_in[1];
  const float* beta  = (const float*)d_in[2];
  const float* wqkv  = (const float*)d_in[3];
  const float* resk  = (const float*)d_in[4];
  const float* wout  = (const float*)d_in[5];
  const float* bout  = (const float*)d_in[6];
  float* out = (float*)d_out;

  const size_t SL = (size_t)B_*H_*N_*DH_;
  const size_t SM = (size_t)B_*H_*M_*DH_;
  const size_t SP = (size_t)B_*H_*M_*M_;

  bf16* xn  = (bf16*)d_ws;     // reused as: flash partial OP, then pinv P1..P4, then outh
  bf16* q   = xn + SL;
  bf16* k   = q + SL;          // k region dead after flash_split -> holds bf16 pinv scratch
  bf16* v   = k + SL;
  bf16* vT  = v + SL;
  bf16* ql  = vT + SL;
  bf16* kl  = ql + SM;
  bf16* kv3 = kl + SM;
  bf16* z2T = kv3 + SM;
  float* A2 = (float*)(z2T + SM);
  bf16* WT  = (bf16*)(A2 + SP);       // 1536 x 512 bf16
  bf16* WT2 = WT + (size_t)1536*512;  // 512 x 512 bf16
  float* P1 = (float*)xn;             // pinv fp32 scratch aliases xn (4*SP*4B == SL*2B)
  float* P2 = P1 + SP;
  float* P3 = P2 + SP;
  float* P4 = P3 + SP;
  float* OPp = (float*)xn;            // flash partials alias xn (dead before pinv)
  float* LPp = (float*)z2T;           // and z2T (dead until gemm_z2)
  // bf16 pinv scratch in dead k region (6*SP*2B = 25.2MB <= 33.5MB)
  bf16* A2b = k;
  bf16* Zb0 = A2b + SP;
  bf16* Zb1 = Zb0 + SP;
  bf16* Pb  = Zb1 + SP;
  bf16* Tb  = Pb + SP;
  bf16* Ub  = Tb + SP;

  k_wt<<<dim3(24, 8), 256, 0, stream>>>(wqkv, WT, 512, 1536);
  k_wt<<<dim3(8, 8), 256, 0, stream>>>(wout, WT2, 512, 512);
  k_layernorm<<<B_*N_, 256, 0, stream>>>(x, gamma, beta, xn);
  k_mm_qkv4<<<dim3(6, 256), 256, 0, stream>>>(xn, WT, q, k, v, vT, ql, kl);

  // attn3 flash (split + merge) BEFORE pinv so partials use the dead xn/z2T regions
  k_flash_split<<<dim3(NSPLIT, B_*H_), 256, 0, stream>>>(ql, k, vT, OPp, LPp);
  k_flash_merge<<<dim3(M_/4, B_*H_), 256, 0, stream>>>(OPp, LPp, kv3);

  k_attn2<<<B_*H_*M_, 256, 0, stream>>>(ql, kl, A2, A2b);
  k_pinv_init<<<B_*H_, 256, 0, stream>>>(A2, Zb0);

  // NS iterations 0-4: pure bf16 (ops already bf16-rounded in plain mode; storage matches)
  bf16* Zbi = Zb0; bf16* Zbo = Zb1;
  for (int it=0; it<5; ++it){
    k_gemm_pmb<<<dim3(16,32), 256, 0, stream>>>(Pb,  A2b, Zbi, 0.f,0, 0.f,0, 1.f);   // P = A2@Z
    k_gemm_pmb<<<dim3(16,32), 256, 0, stream>>>(Tb,  Pb,  Pb,  7.f,1, 15.f,1, 1.f);  // S = 15I-P@(7I-P)
    k_gemm_pmb<<<dim3(16,32), 256, 0, stream>>>(Ub,  Pb,  Tb,  0.f,0, 13.f,1, 1.f);  // U = 13I-P@S
    k_gemm_pmb<<<dim3(16,32), 256, 0, stream>>>(Zbo, Zbi, Ub,  0.f,0, 0.f,0, 0.25f); // Zn = .25*Z@U
    bf16* tt = Zbi; Zbi = Zbo; Zbo = tt;
  }
  // NS iteration 5: split precision fp32 (bf16 operands where exact: lo=0)
  k_gemm_pm<<<dim3(16,32), 256, 0, stream>>>(P2, A2, Zbi, 0.f,0, 0.f,0, 1.f,  0,1); // P
  k_gemm_pm<<<dim3(16,32), 256, 0, stream>>>(P3, P2, P2,  7.f,1, 15.f,1, 1.f, 0,0); // S
  k_gemm_pm<<<dim3(16,32), 256, 0, stream>>>(P4, P2, P3,  0.f,0, 13.f,1, 1.f, 0,0); // U
  k_gemm_pm<<<dim3(16,32), 256, 0, stream>>>(P1, Zbi, P4, 0.f,0, 0.f,0, 0.25f,1,0); // Zn->P1

  k_gemm_z2<<<dim3(4, B_*H_), 256, 0, stream>>>(z2T, P1, kv3);
  k_flash_w3<<<dim3(N_/256, B_*H_), 256, 0, stream>>>(q, kl, z2T, xn);
  k_conv_add<<<dim3(N_/CCH, B_*H_), 256, 0, stream>>>(v, resk, xn);
  k_mm_out2<<<1024, 256, 0, stream>>>(xn, WT2, bout, x, out);
}

// Round 11
// 704.794 us; speedup vs baseline: 1.1687x; 1.0038x over previous
//
#include <hip/hip_runtime.h>
#include <hip/hip_bf16.h>

#define B_ 4
#define N_ 8192
#define D_ 512
#define H_ 8
#define DH_ 64
#define M_ 256
#define LCH 32
#define KER_ 33
#define NSPLIT 16
#define CS (N_/NSPLIT)   // 512 cols per split chunk

typedef __hip_bfloat16 bf16;
typedef __attribute__((ext_vector_type(8))) short short8;
typedef __attribute__((ext_vector_type(4))) short short4v;
typedef __attribute__((ext_vector_type(4))) float f32x4;

__device__ __forceinline__ float bf2f(bf16 h){ return __bfloat162float(h); }
__device__ __forceinline__ bf16 f2bf(float f){ return __float2bfloat16(f); }
__device__ __forceinline__ f32x4 mfma16(short8 a, short8 b, f32x4 c){
  return __builtin_amdgcn_mfma_f32_16x16x32_bf16(a, b, c, 0, 0, 0);
}

// ---------------- LayerNorm: x (b,n,512) fp32 -> xn bf16 ----------------
__global__ __launch_bounds__(256) void k_layernorm(const float* __restrict__ x,
    const float* __restrict__ gamma, const float* __restrict__ beta,
    bf16* __restrict__ xn){
  int row = blockIdx.x;
  const float* xr = x + (size_t)row * D_;
  bf16* o = xn + (size_t)row * D_;
  int t = threadIdx.x;
  float v0 = xr[t], v1 = xr[t+256];
  float s = v0+v1, ss = v0*v0 + v1*v1;
  __shared__ float sh[8];
  for (int off=32; off; off>>=1){ s += __shfl_xor(s,off); ss += __shfl_xor(ss,off); }
  int lane = t&63, wid = t>>6;
  if (lane==0){ sh[wid] = s; sh[wid+4] = ss; }
  __syncthreads();
  float S  = sh[0]+sh[1]+sh[2]+sh[3];
  float SS = sh[4]+sh[5]+sh[6]+sh[7];
  float mu = S*(1.f/D_);
  float var = SS*(1.f/D_) - mu*mu;
  float rs = rsqrtf(var + 1e-5f);
  o[t]     = f2bf((v0-mu)*rs*gamma[t]     + beta[t]);
  o[t+256] = f2bf((v1-mu)*rs*gamma[t+256] + beta[t+256]);
}

// ---------------- W transpose+convert, both weights in ONE launch ----------------
// grid (32,8): blocks 0..23 -> wqkv (C=1536), 24..31 -> wout (C=512). R=512 both.
__global__ __launch_bounds__(256) void k_wt2(const float* __restrict__ W1, bf16* __restrict__ WT1,
    const float* __restrict__ W2, bf16* __restrict__ WT2o){
  int bx = blockIdx.x;
  const float* W; bf16* WT; int C, cx;
  if (bx < 24){ W = W1; WT = WT1; C = 1536; cx = bx; }
  else        { W = W2; WT = WT2o; C = 512;  cx = bx - 24; }
  int c0 = cx*64, r0 = blockIdx.y*64;
  __shared__ float tile[64][65];
  int t = threadIdx.x;
  for (int i=t;i<4096;i+=256){ int r=i>>6, c=i&63; tile[r][c] = W[(size_t)(r0+r)*C + c0+c]; }
  __syncthreads();
  for (int i=t;i<512;i+=256){
    int c=i>>3, rg=i&7;
    short8 o;
    #pragma unroll
    for (int j=0;j<8;j++) ((bf16*)&o)[j] = f2bf(tile[rg*8+j][c]);
    *(short8*)&WT[(size_t)(c0+c)*512 + r0 + rg*8] = o;
  }
}

// ---------------- QKV GEMM (MFMA, 128x256 tile, LDS-transposed full-line epilogue) ----------------
// 2D grid (6,256): XCD swizzle reverted (round 8/9: -70MB FETCH but +25us — not BW-bound).
// Pass-B transposed-ebuf vT write + fused landmark means.
__global__ __launch_bounds__(256, 2) void k_mm_qkv4(const bf16* __restrict__ A, const bf16* __restrict__ WT,
    bf16* __restrict__ qbuf, bf16* __restrict__ kbuf, bf16* __restrict__ vbuf,
    bf16* __restrict__ vT, bf16* __restrict__ qlb, bf16* __restrict__ klb){
  __shared__ __align__(16) bf16 smem[3*128*72];
  bf16 (*As)[72]  = (bf16(*)[72])smem;
  bf16 (*Bs0)[72] = (bf16(*)[72])(smem + 128*72);
  bf16 (*Bs1)[72] = (bf16(*)[72])(smem + 2*128*72);
  bf16 (*ebuf)[136] = (bf16(*)[136])smem;   // epilogue reuse
  int t = threadIdx.x;
  int w = t>>6, lane = t&63, qd = lane>>4, n = lane&15;
  int wm = w>>1, wn = w&1;
  int r0 = blockIdx.y*128, c0 = blockIdx.x*256;
  f32x4 acc[2][4][4];
  #pragma unroll
  for (int cb=0;cb<2;cb++)
    #pragma unroll
    for (int i=0;i<4;i++)
      #pragma unroll
      for (int j=0;j<4;j++) acc[cb][i][j] = (f32x4){0.f,0.f,0.f,0.f};
  int srow = t>>3, skc = t&7;
  for (int k0=0; k0<512; k0+=64){
    #pragma unroll
    for (int ch=0; ch<4; ch++){
      int m = ch*32 + srow;
      *(short8*)&As[m][skc*8]  = *(const short8*)&A [(size_t)(r0+m)*512 + k0 + skc*8];
      *(short8*)&Bs0[m][skc*8] = *(const short8*)&WT[(size_t)(c0+m)*512 + k0 + skc*8];
      *(short8*)&Bs1[m][skc*8] = *(const short8*)&WT[(size_t)(c0+128+m)*512 + k0 + skc*8];
    }
    __syncthreads();
    #pragma unroll
    for (int ksub=0; ksub<2; ksub++){
      short8 af[4];
      #pragma unroll
      for (int i=0;i<4;i++) af[i] = *(const short8*)&As[wm*64+i*16+n][ksub*32+qd*8];
      #pragma unroll
      for (int cb=0; cb<2; cb++){
        bf16 (*Bsc)[72] = cb ? Bs1 : Bs0;
        short8 bfr[4];
        #pragma unroll
        for (int j=0;j<4;j++) bfr[j] = *(const short8*)&Bsc[wn*64+j*16+n][ksub*32+qd*8];
        #pragma unroll
        for (int i=0;i<4;i++)
          #pragma unroll
          for (int j=0;j<4;j++) acc[cb][i][j] = mfma16(af[i], bfr[j], acc[cb][i][j]);
      }
    }
    __syncthreads();
  }
  int part = c0 >> 9;   // uniform per block
  bf16* dst = (part==0)? qbuf : (part==1)? kbuf : vbuf;
  float scale = (part==0)? 0.125f : 1.f;
  int b = r0 >> 13, nn = r0 & 8191;
  #pragma unroll
  for (int cb=0; cb<2; cb++){
    __syncthreads();
    #pragma unroll
    for (int i=0;i<4;i++)
      #pragma unroll
      for (int j=0;j<4;j++)
        #pragma unroll
        for (int rg=0; rg<4; rg++)
          ebuf[wm*64+i*16+qd*4+rg][wn*64+j*16+n] = f2bf(acc[cb][i][j][rg]*scale);
    __syncthreads();
    #pragma unroll
    for (int rep=0; rep<8; rep++){
      int unit = rep*256 + t;
      int row = unit >> 4, ch = unit & 15;
      int col = c0 + cb*128 + ch*8;
      int cc = col & 511, h = cc>>6, dh = cc&63;
      *(short8*)&dst[(((size_t)(b*H_+h))*N_ + nn + row)*DH_ + dh] = *(const short8*)&ebuf[row][ch*8];
    }
    if (part < 2){
      bf16* lt = (part==0) ? qlb : klb;
      #pragma unroll
      for (int rep=0; rep<2; rep++){
        int oi = rep*256 + t;          // 0..511: chunk(4) x col(128)
        int chunk = oi >> 7, col = oi & 127;
        float sum = 0.f;
        #pragma unroll
        for (int rr=0; rr<32; rr++) sum += bf2f(ebuf[chunk*32+rr][col]);
        int m = (nn >> 5) + chunk;
        int cc = (c0 + cb*128 + col) & 511;
        int h = cc >> 6, dh = cc & 63;
        lt[(((size_t)(b*H_+h))*M_ + m)*DH_ + dh] = f2bf(sum * (1.f/LCH));
      }
    } else {
      // pass B: refill ebuf TRANSPOSED from acc; 8B ds_writes, then full-line vT stores.
      __syncthreads();
      #pragma unroll
      for (int i=0;i<4;i++)
        #pragma unroll
        for (int j=0;j<4;j++){
          short4v tv;
          #pragma unroll
          for (int rg=0; rg<4; rg++) ((bf16*)&tv)[rg] = f2bf(acc[cb][i][j][rg]);
          *(short4v*)&ebuf[wn*64+j*16+n][wm*64+i*16+qd*4] = tv;
        }
      __syncthreads();
      #pragma unroll
      for (int rep=0; rep<8; rep++){
        int unit = rep*256 + t;        // col(128) x ch(16)
        int col = unit >> 4, ch = unit & 15;
        int cc = (c0 + cb*128 + col) & 511;
        int h = cc >> 6, dh = cc & 63;
        *(short8*)&vT[(((size_t)(b*H_+h))*DH_ + dh)*N_ + nn + ch*8] = *(const short8*)&ebuf[col][ch*8];
      }
    }
  }
}

// ---------------- attn2 = softmax(q_l @ k_l^T), no-max (|s|<=~2, same as flash kernels) ----------------
__global__ __launch_bounds__(256) void k_attn2(const bf16* __restrict__ ql, const bf16* __restrict__ kl,
    float* __restrict__ A2, bf16* __restrict__ A2b){
  int bhm = blockIdx.x;
  int bh = bhm >> 8, m = bhm & 255;
  int t = threadIdx.x;
  __shared__ float qrow[64];
  __shared__ float sh[4];
  if (t < 64) qrow[t] = bf2f(ql[((size_t)bh*M_ + m)*DH_ + t]);
  __syncthreads();
  const bf16* krow = kl + ((size_t)bh*M_ + t)*DH_;
  float s = 0.f;
  #pragma unroll
  for (int i=0;i<64;i++) s += qrow[i]*bf2f(krow[i]);
  float e = __expf(s);
  float sum = e;
  for (int off=32; off; off>>=1) sum += __shfl_xor(sum, off);
  if ((t&63)==0) sh[t>>6] = sum;
  __syncthreads();
  sum = sh[0]+sh[1]+sh[2]+sh[3];
  float r = e/sum;
  A2[((size_t)bh*M_ + m)*M_ + t] = r;
  A2b[((size_t)bh*M_ + m)*M_ + t] = f2bf(r);
}

// ---------------- pinv init: Z = A^T / max_colsum  (softmax rows sum to 1 -> maxr==1) ----------------
__global__ __launch_bounds__(256) void k_pinv_init(const float* __restrict__ A2, bf16* __restrict__ Z){
  int bh = blockIdx.x;
  int t = threadIdx.x;
  const float* Ab = A2 + (size_t)bh*M_*M_;
  bf16* Zb = Z + (size_t)bh*M_*M_;
  float cs=0.f;
  for (int r=0;r<M_;r++) cs += Ab[(size_t)r*M_ + t];   // entries positive
  __shared__ float sh[4];
  float v = cs;
  for (int off=32; off; off>>=1) v = fmaxf(v, __shfl_xor(v, off));
  if ((t&63)==0) sh[t>>6] = v;
  __syncthreads();
  float maxc = fmaxf(fmaxf(sh[0],sh[1]), fmaxf(sh[2],sh[3]));
  float inv = 1.f/maxc;
  for (int r=0;r<M_;r++) Zb[(size_t)r*M_ + t] = f2bf(Ab[(size_t)t*M_ + r]*inv);
}

// ---------------- pinv GEMM, pure bf16, K staged in 2 chunks of 128 (halved barriers) ----------------
__global__ __launch_bounds__(256) void k_gemm_pmb(bf16* __restrict__ C, const bf16* __restrict__ A,
    const bf16* __restrict__ Bm, float bDiag, int bNeg, float cDiag, int cNeg, float cScale){
  int bh = blockIdx.y;
  int tm = blockIdx.x >> 2, tn = blockIdx.x & 3;
  const bf16* Ab = A  + (size_t)bh*65536;
  const bf16* Bb = Bm + (size_t)bh*65536;
  bf16* Cb = C + (size_t)bh*65536;
  __shared__ __align__(16) bf16 Ah[64][136];
  __shared__ __align__(16) bf16 Bh[64][136];
  int t = threadIdx.x;
  int w = t>>6, lane = t&63, qd = lane>>4, n = lane&15;
  int wm = w>>1, wn = w&1;
  int r0 = tm*64, c0 = tn*64;
  f32x4 acc[2][2];
  #pragma unroll
  for (int i=0;i<2;i++)
    #pragma unroll
    for (int j=0;j<2;j++) acc[i][j] = (f32x4){0.f,0.f,0.f,0.f};
  int arow = t>>2, akc = (t&3)*32;     // A: 64 rows x 128 k per chunk
  int bkrow = t>>1, bcc = (t&1)*32;    // B: 128 k-rows x 64 cols per chunk
  for (int k0=0; k0<256; k0+=128){
    #pragma unroll
    for (int vv=0; vv<4; vv++)
      *(short8*)&Ah[arow][akc+vv*8] = *(const short8*)&Ab[(size_t)(r0+arow)*256 + k0+akc+vv*8];
    int kr = k0 + bkrow;
    #pragma unroll
    for (int vv=0; vv<4; vv++){
      short8 vb = *(const short8*)&Bb[(size_t)kr*256 + c0 + bcc + vv*8];
      if (bNeg){
        #pragma unroll
        for (int j=0;j<8;j++){
          float x = (kr == (c0 + bcc + vv*8 + j) ? bDiag : 0.f) - bf2f(((bf16*)&vb)[j]);
          Bh[bcc+vv*8+j][bkrow] = f2bf(x);
        }
      } else {
        #pragma unroll
        for (int j=0;j<8;j++) Bh[bcc+vv*8+j][bkrow] = ((bf16*)&vb)[j];
      }
    }
    __syncthreads();
    #pragma unroll
    for (int ksub=0; ksub<4; ksub++){
      short8 afh[2], bfh[2];
      #pragma unroll
      for (int i=0;i<2;i++) afh[i] = *(const short8*)&Ah[wm*32+i*16+n][ksub*32+qd*8];
      #pragma unroll
      for (int j=0;j<2;j++) bfh[j] = *(const short8*)&Bh[wn*32+j*16+n][ksub*32+qd*8];
      #pragma unroll
      for (int i=0;i<2;i++)
        #pragma unroll
        for (int j=0;j<2;j++) acc[i][j] = mfma16(afh[i], bfh[j], acc[i][j]);
    }
    __syncthreads();
  }
  #pragma unroll
  for (int i=0;i<2;i++){
    #pragma unroll
    for (int j=0;j<2;j++){
      int cidx = c0 + wn*32 + j*16 + n;
      #pragma unroll
      for (int rg=0; rg<4; rg++){
        int r = r0 + wm*32 + i*16 + qd*4 + rg;
        float r_ = acc[i][j][rg];
        if (cNeg) r_ = ((r==cidx)? cDiag : 0.f) - r_;
        Cb[(size_t)r*256 + cidx] = f2bf(r_*cScale);
      }
    }
  }
}

// ---------------- pinv GEMM fp32 (split precision; aBf/bBf: operand is bf16, lo=0) ----------------
// NOTE (round 4): do NOT fuse via cooperative grid.sync — device-scope fences defeat
// cross-XCD cache reuse (560MB HBM refetch, 23x slower). Small launches win.
__global__ __launch_bounds__(256) void k_gemm_pm(float* __restrict__ C, const void* __restrict__ Av,
    const void* __restrict__ Bv, float bDiag, int bNeg, float cDiag, int cNeg, float cScale,
    int aBf, int bBf){
  int bh = blockIdx.y;
  int tm = blockIdx.x >> 2, tn = blockIdx.x & 3;
  const float* Af = (const float*)Av; const bf16* A16 = (const bf16*)Av;
  const float* Bf = (const float*)Bv; const bf16* B16 = (const bf16*)Bv;
  float* Cb = C + (size_t)bh*65536;
  __shared__ __align__(16) bf16 Ah[64][72];
  __shared__ __align__(16) bf16 Al[64][72];
  __shared__ __align__(16) bf16 Bh[64][72];
  __shared__ __align__(16) bf16 Bl[64][72];
  int t = threadIdx.x;
  int w = t>>6, lane = t&63, qd = lane>>4, n = lane&15;
  int wm = w>>1, wn = w&1;
  int r0 = tm*64, c0 = tn*64;
  f32x4 acc[2][2];
  #pragma unroll
  for (int i=0;i<2;i++)
    #pragma unroll
    for (int j=0;j<2;j++) acc[i][j] = (f32x4){0.f,0.f,0.f,0.f};
  int srow = t>>3, skc = t&7;
  for (int k0=0; k0<256; k0+=64){
    #pragma unroll
    for (int ch=0; ch<2; ch++){
      int m = ch*32 + srow;
      if (aBf){
        *(short8*)&Ah[m][skc*8] = *(const short8*)&A16[(size_t)bh*65536 + (size_t)(r0+m)*256 + k0 + skc*8];
      } else {
        short8 vh, vl;
        const float* ap = &Af[(size_t)bh*65536 + (size_t)(r0+m)*256 + k0 + skc*8];
        #pragma unroll
        for (int j=0;j<8;j++){
          float x = ap[j];
          bf16 h = f2bf(x);
          ((bf16*)&vh)[j] = h;
          ((bf16*)&vl)[j] = f2bf(x - bf2f(h));
        }
        *(short8*)&Ah[m][skc*8] = vh;
        *(short8*)&Al[m][skc*8] = vl;
      }
      int kr = k0 + m;
      if (bBf){
        short8 vb = *(const short8*)&B16[(size_t)bh*65536 + (size_t)(k0+m)*256 + c0 + skc*8];
        #pragma unroll
        for (int j=0;j<8;j++) Bh[skc*8+j][m] = ((bf16*)&vb)[j];  // bBf only used with bNeg==0
      } else {
        const float* bp = &Bf[(size_t)bh*65536 + (size_t)(k0+m)*256 + c0 + skc*8];
        #pragma unroll
        for (int j=0;j<8;j++){
          float x = bp[j];
          if (bNeg) x = (kr == (c0 + skc*8 + j) ? bDiag : 0.f) - x;
          bf16 h = f2bf(x);
          Bh[skc*8+j][m] = h;
          Bl[skc*8+j][m] = f2bf(x - bf2f(h));
        }
      }
    }
    __syncthreads();
    #pragma unroll
    for (int ksub=0; ksub<2; ksub++){
      short8 afh[2], afl[2], bfh[2], bfl[2];
      #pragma unroll
      for (int i=0;i<2;i++){
        afh[i] = *(const short8*)&Ah[wm*32+i*16+n][ksub*32+qd*8];
        if (!aBf) afl[i] = *(const short8*)&Al[wm*32+i*16+n][ksub*32+qd*8];
      }
      #pragma unroll
      for (int j=0;j<2;j++){
        bfh[j] = *(const short8*)&Bh[wn*32+j*16+n][ksub*32+qd*8];
        if (!bBf) bfl[j] = *(const short8*)&Bl[wn*32+j*16+n][ksub*32+qd*8];
      }
      #pragma unroll
      for (int i=0;i<2;i++)
        #pragma unroll
        for (int j=0;j<2;j++){
          if (!aBf) acc[i][j] = mfma16(afl[i], bfh[j], acc[i][j]);
          if (!bBf) acc[i][j] = mfma16(afh[i], bfl[j], acc[i][j]);
          acc[i][j] = mfma16(afh[i], bfh[j], acc[i][j]);
        }
    }
    __syncthreads();
  }
  #pragma unroll
  for (int i=0;i<2;i++){
    #pragma unroll
    for (int j=0;j<2;j++){
      int cidx = c0 + wn*32 + j*16 + n;
      #pragma unroll
      for (int rg=0; rg<4; rg++){
        int r = r0 + wm*32 + i*16 + qd*4 + rg;
        float r_ = acc[i][j][rg];
        if (cNeg) r_ = ((r==cidx)? cDiag : 0.f) - r_;
        Cb[(size_t)r*256 + cidx] = r_*cScale;
      }
    }
  }
}

// ---------------- batched GEMM 256x64x256: z2T = (Z @ kv3)^T ----------------
__global__ __launch_bounds__(256) void k_gemm_z2(bf16* __restrict__ z2t, const float* __restrict__ A,
    const bf16* __restrict__ Bm){
  int bh = blockIdx.y;
  int tm = blockIdx.x;
  const float* Ab = A  + (size_t)bh*65536;
  const bf16* Bb = Bm + (size_t)bh*M_*DH_;
  __shared__ float As[16][68];
  __shared__ float Bs[16][64];
  int t = threadIdx.x, tx = t&15, ty = t>>4;
  int r0 = tm*64;
  float acc[4][4] = {};
  for (int k0=0;k0<256;k0+=16){
    for (int i=t;i<1024;i+=256){
      int m=i>>4, kq=i&15;
      As[kq][m] = Ab[(size_t)(r0+m)*256 + k0+kq];
      int nn=i&63, k2=i>>6;
      Bs[k2][nn] = bf2f(Bb[(size_t)(k0+k2)*64 + nn]);
    }
    __syncthreads();
    #pragma unroll
    for (int kq=0;kq<16;kq++){
      float a0[4], b0[4];
      #pragma unroll
      for (int i=0;i<4;i++) a0[i] = As[kq][ty*4+i];
      #pragma unroll
      for (int j=0;j<4;j++) b0[j] = Bs[kq][tx*4+j];
      #pragma unroll
      for (int i=0;i<4;i++)
        #pragma unroll
        for (int j=0;j<4;j++) acc[i][j] += a0[i]*b0[j];
    }
    __syncthreads();
  }
  #pragma unroll
  for (int i=0;i<4;i++){
    int r = r0+ty*4+i;
    #pragma unroll
    for (int j=0;j<4;j++)
      z2t[(size_t)bh*16384 + (size_t)(tx*4+j)*256 + r] = f2bf(acc[i][j]);
  }
}

// ---------------- attn3 flash, no-max softmax ----------------
__global__ __launch_bounds__(256, 2) void k_flash_split(const bf16* __restrict__ Q,
    const bf16* __restrict__ K, const bf16* __restrict__ VT,
    float* __restrict__ OP, float* __restrict__ LP){
  int bh = blockIdx.y;
  int sp = blockIdx.x;
  int t = threadIdx.x, w = t>>6, lane = t&63, qd = lane>>4, n = lane&15;
  int r0 = w*64;
  const size_t Qoff = ((size_t)bh*M_ + r0)*DH_;
  const size_t Koff = ((size_t)bh*N_ + (size_t)sp*CS)*DH_;
  const size_t Voff = (size_t)bh*DH_*N_ + (size_t)sp*CS;
  __shared__ __align__(16) bf16 pbuf[4][4][16][72];
  short8 aq[4][2];
  #pragma unroll
  for (int rt=0; rt<4; rt++){
    aq[rt][0] = *(const short8*)&Q[Qoff + (size_t)(rt*16+n)*DH_ + qd*8];
    aq[rt][1] = *(const short8*)&Q[Qoff + (size_t)(rt*16+n)*DH_ + 32 + qd*8];
  }
  f32x4 o[4][4];
  float lrun[4][4];
  #pragma unroll
  for (int rt=0; rt<4; rt++){
    #pragma unroll
    for (int j=0;j<4;j++){ o[rt][j] = (f32x4){0.f,0.f,0.f,0.f}; lrun[rt][j] = 0.f; }
  }
  for (int tl=0; tl<CS/64; ++tl){
    const bf16* kp = K + Koff + (size_t)(tl*64)*DH_;
    short8 kb[4][2];
    #pragma unroll
    for (int cg=0; cg<4; cg++){
      kb[cg][0] = *(const short8*)&kp[(size_t)(cg*16+n)*DH_ + qd*8];
      kb[cg][1] = *(const short8*)&kp[(size_t)(cg*16+n)*DH_ + 32 + qd*8];
    }
    #pragma unroll
    for (int rt=0; rt<4; rt++){
      f32x4 s[4];
      #pragma unroll
      for (int cg=0; cg<4; cg++){
        f32x4 z = (f32x4){0.f,0.f,0.f,0.f};
        z = mfma16(aq[rt][0], kb[cg][0], z);
        z = mfma16(aq[rt][1], kb[cg][1], z);
        s[cg] = z;
      }
      #pragma unroll
      for (int rg=0; rg<4; rg++){
        float p0 = __expf(s[0][rg]), p1 = __expf(s[1][rg]);
        float p2 = __expf(s[2][rg]), p3 = __expf(s[3][rg]);
        float ts = p0+p1+p2+p3;
        ts += __shfl_xor(ts,1); ts += __shfl_xor(ts,2);
        ts += __shfl_xor(ts,4); ts += __shfl_xor(ts,8);
        lrun[rt][rg] += ts;
        pbuf[w][rt][qd*4+rg][n]    = f2bf(p0);
        pbuf[w][rt][qd*4+rg][16+n] = f2bf(p1);
        pbuf[w][rt][qd*4+rg][32+n] = f2bf(p2);
        pbuf[w][rt][qd*4+rg][48+n] = f2bf(p3);
      }
    }
    const bf16* vp = VT + Voff + tl*64 + qd*8;
    short8 vb[4][2];
    #pragma unroll
    for (int dg=0; dg<4; dg++){
      vb[dg][0] = *(const short8*)&vp[(size_t)(dg*16+n)*N_];
      vb[dg][1] = *(const short8*)&vp[(size_t)(dg*16+n)*N_ + 32];
    }
    #pragma unroll
    for (int rt=0; rt<4; rt++){
      short8 ap0 = *(const short8*)&pbuf[w][rt][n][qd*8];
      short8 ap1 = *(const short8*)&pbuf[w][rt][n][32+qd*8];
      #pragma unroll
      for (int dg=0; dg<4; dg++){
        o[rt][dg] = mfma16(ap0, vb[dg][0], o[rt][dg]);
        o[rt][dg] = mfma16(ap1, vb[dg][1], o[rt][dg]);
      }
    }
  }
  size_t base = ((size_t)sp*(B_*H_) + bh)*M_;
  #pragma unroll
  for (int rt=0; rt<4; rt++){
    #pragma unroll
    for (int rg=0; rg<4; rg++){
      int row = r0 + rt*16 + qd*4 + rg;
      if (n==0) LP[base+row] = lrun[rt][rg];
      #pragma unroll
      for (int dg=0; dg<4; dg++)
        OP[(base+row)*DH_ + dg*16 + n] = o[rt][dg][rg];
    }
  }
}

// ---------------- merge NSPLIT flash partials -> kv3 (plain sums) ----------------
__global__ __launch_bounds__(256) void k_flash_merge(const float* __restrict__ OP,
    const float* __restrict__ LP, bf16* __restrict__ O){
  int bh = blockIdx.y;
  int r = blockIdx.x*4 + (threadIdx.x>>6);
  int dh = threadIdx.x & 63;
  float acc = 0.f, den = 0.f;
  for (int s=0; s<NSPLIT; s++){
    size_t base = ((size_t)s*(B_*H_) + bh)*M_ + r;
    den += LP[base];
    acc += OP[base*DH_ + dh];
  }
  O[((size_t)bh*M_ + r)*DH_ + dh] = f2bf(acc/den);
}

// ---------------- attn1 flash, no-max softmax, 4 waves x 4 rowtiles ----------------
__global__ __launch_bounds__(256, 2) void k_flash_w3(const bf16* __restrict__ Q,
    const bf16* __restrict__ K, const bf16* __restrict__ VT, bf16* __restrict__ O){
  int bh = blockIdx.y;
  int t = threadIdx.x, w = t>>6, lane = t&63, qd = lane>>4, n = lane&15;
  int r0 = blockIdx.x*256 + w*64;
  const size_t Qoff = ((size_t)bh*N_ + r0)*DH_;
  const size_t Koff = (size_t)bh*M_*DH_;
  const size_t Voff = (size_t)bh*DH_*M_;
  __shared__ __align__(16) bf16 pbuf[4][4][16][72];
  short8 aq[4][2];
  #pragma unroll
  for (int rt=0; rt<4; rt++){
    aq[rt][0] = *(const short8*)&Q[Qoff + (size_t)(rt*16+n)*DH_ + qd*8];
    aq[rt][1] = *(const short8*)&Q[Qoff + (size_t)(rt*16+n)*DH_ + 32 + qd*8];
  }
  f32x4 o[4][4];
  float lrun[4][4];
  #pragma unroll
  for (int rt=0; rt<4; rt++){
    #pragma unroll
    for (int j=0;j<4;j++){ o[rt][j] = (f32x4){0.f,0.f,0.f,0.f}; lrun[rt][j] = 0.f; }
  }
  #pragma unroll
  for (int tl=0; tl<4; ++tl){
    const bf16* kp = K + Koff + (size_t)(tl*64)*DH_;
    short8 kb[4][2];
    #pragma unroll
    for (int cg=0; cg<4; cg++){
      kb[cg][0] = *(const short8*)&kp[(size_t)(cg*16+n)*DH_ + qd*8];
      kb[cg][1] = *(const short8*)&kp[(size_t)(cg*16+n)*DH_ + 32 + qd*8];
    }
    #pragma unroll
    for (int rt=0; rt<4; rt++){
      f32x4 s[4];
      #pragma unroll
      for (int cg=0; cg<4; cg++){
        f32x4 z = (f32x4){0.f,0.f,0.f,0.f};
        z = mfma16(aq[rt][0], kb[cg][0], z);
        z = mfma16(aq[rt][1], kb[cg][1], z);
        s[cg] = z;
      }
      #pragma unroll
      for (int rg=0; rg<4; rg++){
        float p0 = __expf(s[0][rg]), p1 = __expf(s[1][rg]);
        float p2 = __expf(s[2][rg]), p3 = __expf(s[3][rg]);
        float ts = p0+p1+p2+p3;
        ts += __shfl_xor(ts,1); ts += __shfl_xor(ts,2);
        ts += __shfl_xor(ts,4); ts += __shfl_xor(ts,8);
        lrun[rt][rg] += ts;
        pbuf[w][rt][qd*4+rg][n]    = f2bf(p0);
        pbuf[w][rt][qd*4+rg][16+n] = f2bf(p1);
        pbuf[w][rt][qd*4+rg][32+n] = f2bf(p2);
        pbuf[w][rt][qd*4+rg][48+n] = f2bf(p3);
      }
    }
    const bf16* vp = VT + Voff + tl*64 + qd*8;
    short8 vb[4][2];
    #pragma unroll
    for (int dg=0; dg<4; dg++){
      vb[dg][0] = *(const short8*)&vp[(size_t)(dg*16+n)*M_];
      vb[dg][1] = *(const short8*)&vp[(size_t)(dg*16+n)*M_ + 32];
    }
    #pragma unroll
    for (int rt=0; rt<4; rt++){
      short8 ap0 = *(const short8*)&pbuf[w][rt][n][qd*8];
      short8 ap1 = *(const short8*)&pbuf[w][rt][n][32+qd*8];
      #pragma unroll
      for (int dg=0; dg<4; dg++){
        o[rt][dg] = mfma16(ap0, vb[dg][0], o[rt][dg]);
        o[rt][dg] = mfma16(ap1, vb[dg][1], o[rt][dg]);
      }
    }
  }
  #pragma unroll
  for (int rt=0; rt<4; rt++){
    #pragma unroll
    for (int rg=0; rg<4; rg++){
      float inv = 1.f/lrun[rt][rg];
      size_t rowoff = ((size_t)bh*N_ + r0 + rt*16 + qd*4 + rg)*DH_;
      #pragma unroll
      for (int dg=0; dg<4; dg++)
        O[rowoff + dg*16 + n] = f2bf(o[rt][dg][rg]*inv);
    }
  }
}

// ---------------- depthwise conv(KER=33): CCH=128, prefetched RMW, unroll x3 ----------------
#define CCH 128
__global__ __launch_bounds__(256, 4) void k_conv_add(const bf16* __restrict__ v, const float* __restrict__ w,
    bf16* __restrict__ outh){
  int bh = blockIdx.y;
  int n0 = blockIdx.x * CCH;
  int h = bh & 7;
  __shared__ bf16 vs[CCH+32][72];
  __shared__ float wk[KER_];
  int t = threadIdx.x;
  if (t < KER_) wk[t] = w[h*KER_ + t];
  const bf16* vb = v + (size_t)bh*N_*DH_;
  for (int i=t; i<(CCH+32)*8; i+=256){
    int r = i>>3, cg = i&7;
    int nn = n0 - 16 + r;
    short8 val = {0,0,0,0,0,0,0,0};
    if (nn >= 0 && nn < N_) val = *(const short8*)&vb[(size_t)nn*DH_ + cg*8];
    *(short8*)&vs[r][cg*8] = val;
  }
  __syncthreads();
  int dhg = t & 7, rowg = t >> 3;
  bf16* ob = outh + ((size_t)bh*N_ + n0)*DH_;
  #pragma unroll
  for (int rr=0; rr<4; rr++){
    int lr = rowg*4 + rr;
    short8 o = *(short8*)&ob[(size_t)lr*DH_ + dhg*8];   // issue RMW load before taps
    float acc[8] = {0.f,0.f,0.f,0.f,0.f,0.f,0.f,0.f};
    #pragma unroll 3
    for (int tt=0; tt<KER_; tt++){
      short8 vv = *(const short8*)&vs[lr+tt][dhg*8];
      float wt = wk[tt];
      #pragma unroll
      for (int j=0;j<8;j++) acc[j] += wt * bf2f(((bf16*)&vv)[j]);
    }
    #pragma unroll
    for (int j=0;j<8;j++) ((bf16*)&o)[j] = f2bf(bf2f(((bf16*)&o)[j]) + acc[j]);
    *(short8*)&ob[(size_t)lr*DH_ + dhg*8] = o;
  }
}

// ---------------- final GEMM: out = x + gather(outh) @ WT2^T + b_out ----------------
// 1D grid 1024 with XCD-chunked swizzle (kept: mm_out2 writes fp32 out, more BW-sensitive).
__global__ __launch_bounds__(256) void k_mm_out2(const bf16* __restrict__ Ahd, const bf16* __restrict__ WT2,
    const float* __restrict__ bias, const float* __restrict__ xin, float* __restrict__ out){
  __shared__ __align__(16) bf16 As[128][72];
  __shared__ __align__(16) bf16 Bs[128][72];
  int t = threadIdx.x;
  int w = t>>6, lane = t&63, qd = lane>>4, n = lane&15;
  int wm = w>>1, wn = w&1;
  int bid = blockIdx.x;                // 0..1023
  int xcd = bid & 7, pos = bid >> 3;
  int tid = xcd*128 + pos;
  int cx = tid & 3, ry = tid >> 2;
  int r0 = ry*128, c0 = cx*128;
  f32x4 acc[4][4];
  #pragma unroll
  for (int i=0;i<4;i++)
    #pragma unroll
    for (int j=0;j<4;j++) acc[i][j] = (f32x4){0.f,0.f,0.f,0.f};
  int srow = t>>3, skc = t&7;
  for (int k0=0; k0<512; k0+=64){
    int h = k0 >> 6;
    #pragma unroll
    for (int ch=0; ch<4; ch++){
      int m = ch*32 + srow;
      int r = r0 + m, b = r>>13, nn = r&8191;
      *(short8*)&As[m][skc*8] = *(const short8*)&Ahd[((size_t)(b*H_+h)*N_ + nn)*DH_ + skc*8];
      *(short8*)&Bs[m][skc*8] = *(const short8*)&WT2[(size_t)(c0+m)*512 + k0 + skc*8];
    }
    __syncthreads();
    #pragma unroll
    for (int ksub=0; ksub<2; ksub++){
      short8 af[4], bfr[4];
      #pragma unroll
      for (int i=0;i<4;i++) af[i]  = *(const short8*)&As[wm*64+i*16+n][ksub*32+qd*8];
      #pragma unroll
      for (int j=0;j<4;j++) bfr[j] = *(const short8*)&Bs[wn*64+j*16+n][ksub*32+qd*8];
      #pragma unroll
      for (int i=0;i<4;i++)
        #pragma unroll
        for (int j=0;j<4;j++) acc[i][j] = mfma16(af[i], bfr[j], acc[i][j]);
    }
    __syncthreads();
  }
  #pragma unroll
  for (int i=0;i<4;i++){
    #pragma unroll
    for (int rg=0; rg<4; rg++){
      int r = r0 + wm*64 + i*16 + qd*4 + rg;
      size_t base = (size_t)r*512;
      #pragma unroll
      for (int j=0;j<4;j++){
        int c = c0 + wn*64 + j*16 + n;
        out[base + c] = acc[i][j][rg] + bias[c] + xin[base + c];
      }
    }
  }
}

extern "C" void kernel_launch(void* const* d_in, const int* in_sizes, int n_in,
                              void* d_out, int out_size, void* d_ws, size_t ws_size,
                              hipStream_t stream) {
  const float* x     = (const float*)d_in[0];
  const float* gamma = (const float*)d_in[1];
  const float* beta  = (const float*)d_in[2];
  const float* wqkv  = (const float*)d_in[3];
  const float* resk  = (const float*)d_in[4];
  const float* wout  = (const float*)d_in[5];
  const float* bout  = (const float*)d_in[6];
  float* out = (float*)d_out;

  const size_t SL = (size_t)B_*H_*N_*DH_;
  const size_t SM = (size_t)B_*H_*M_*DH_;
  const size_t SP = (size_t)B_*H_*M_*M_;

  bf16* xn  = (bf16*)d_ws;     // reused as: flash partial OP, then pinv P1..P4, then outh
  bf16* q   = xn + SL;
  bf16* k   = q + SL;          // k region dead after flash_split -> holds bf16 pinv scratch
  bf16* v   = k + SL;
  bf16* vT  = v + SL;
  bf16* ql  = vT + SL;
  bf16* kl  = ql + SM;
  bf16* kv3 = kl + SM;
  bf16* z2T = kv3 + SM;
  float* A2 = (float*)(z2T + SM);
  bf16* WT  = (bf16*)(A2 + SP);       // 1536 x 512 bf16
  bf16* WT2 = WT + (size_t)1536*512;  // 512 x 512 bf16
  float* P1 = (float*)xn;             // pinv fp32 scratch aliases xn (4*SP*4B == SL*2B)
  float* P2 = P1 + SP;
  float* P3 = P2 + SP;
  float* P4 = P3 + SP;
  float* OPp = (float*)xn;            // flash partials alias xn (dead before pinv)
  float* LPp = (float*)z2T;           // and z2T (dead until gemm_z2)
  // bf16 pinv scratch in dead k region (6*SP*2B = 25.2MB <= 33.5MB)
  bf16* A2b = k;
  bf16* Zb0 = A2b + SP;
  bf16* Zb1 = Zb0 + SP;
  bf16* Pb  = Zb1 + SP;
  bf16* Tb  = Pb + SP;
  bf16* Ub  = Tb + SP;

  k_wt2<<<dim3(32, 8), 256, 0, stream>>>(wqkv, WT, wout, WT2);
  k_layernorm<<<B_*N_, 256, 0, stream>>>(x, gamma, beta, xn);
  k_mm_qkv4<<<dim3(6, 256), 256, 0, stream>>>(xn, WT, q, k, v, vT, ql, kl);

  // attn3 flash (split + merge) BEFORE pinv so partials use the dead xn/z2T regions
  k_flash_split<<<dim3(NSPLIT, B_*H_), 256, 0, stream>>>(ql, k, vT, OPp, LPp);
  k_flash_merge<<<dim3(M_/4, B_*H_), 256, 0, stream>>>(OPp, LPp, kv3);

  k_attn2<<<B_*H_*M_, 256, 0, stream>>>(ql, kl, A2, A2b);
  k_pinv_init<<<B_*H_, 256, 0, stream>>>(A2, Zb0);

  // NS iterations 0-4: pure bf16 (ops already bf16-rounded in plain mode; storage matches)
  bf16* Zbi = Zb0; bf16* Zbo = Zb1;
  for (int it=0; it<5; ++it){
    k_gemm_pmb<<<dim3(16,32), 256, 0, stream>>>(Pb,  A2b, Zbi, 0.f,0, 0.f,0, 1.f);   // P = A2@Z
    k_gemm_pmb<<<dim3(16,32), 256, 0, stream>>>(Tb,  Pb,  Pb,  7.f,1, 15.f,1, 1.f);  // S = 15I-P@(7I-P)
    k_gemm_pmb<<<dim3(16,32), 256, 0, stream>>>(Ub,  Pb,  Tb,  0.f,0, 13.f,1, 1.f);  // U = 13I-P@S
    k_gemm_pmb<<<dim3(16,32), 256, 0, stream>>>(Zbo, Zbi, Ub,  0.f,0, 0.f,0, 0.25f); // Zn = .25*Z@U
    bf16* tt = Zbi; Zbi = Zbo; Zbo = tt;
  }
  // NS iteration 5: split precision fp32 (bf16 operands where exact: lo=0)
  k_gemm_pm<<<dim3(16,32), 256, 0, stream>>>(P2, A2, Zbi, 0.f,0, 0.f,0, 1.f,  0,1); // P
  k_gemm_pm<<<dim3(16,32), 256, 0, stream>>>(P3, P2, P2,  7.f,1, 15.f,1, 1.f, 0,0); // S
  k_gemm_pm<<<dim3(16,32), 256, 0, stream>>>(P4, P2, P3,  0.f,0, 13.f,1, 1.f, 0,0); // U
  k_gemm_pm<<<dim3(16,32), 256, 0, stream>>>(P1, Zbi, P4, 0.f,0, 0.f,0, 0.25f,1,0); // Zn->P1

  k_gemm_z2<<<dim3(4, B_*H_), 256, 0, stream>>>(z2T, P1, kv3);
  k_flash_w3<<<dim3(N_/256, B_*H_), 256, 0, stream>>>(q, kl, z2T, xn);
  k_conv_add<<<dim3(N_/CCH, B_*H_), 256, 0, stream>>>(v, resk, xn);
  k_mm_out2<<<1024, 256, 0, stream>>>(xn, WT2, bout, x, out);
}

// Round 13
// 675.429 us; speedup vs baseline: 1.2195x; 1.0435x over previous
//
#include <hip/hip_runtime.h>
#include <hip/hip_bf16.h>

#define B_ 4
#define N_ 8192
#define D_ 512
#define H_ 8
#define DH_ 64
#define M_ 256
#define LCH 32
#define KER_ 33
#define NSPLIT 16
#define CS (N_/NSPLIT)   // 512 cols per split chunk

typedef __hip_bfloat16 bf16;
typedef __attribute__((ext_vector_type(8))) short short8;
typedef __attribute__((ext_vector_type(4))) short short4v;
typedef __attribute__((ext_vector_type(4))) float f32x4;

__device__ __forceinline__ float bf2f(bf16 h){ return __bfloat162float(h); }
__device__ __forceinline__ bf16 f2bf(float f){ return __float2bfloat16(f); }
__device__ __forceinline__ f32x4 mfma16(short8 a, short8 b, f32x4 c){
  return __builtin_amdgcn_mfma_f32_16x16x32_bf16(a, b, c, 0, 0, 0);
}
// async global->LDS, 16B/lane; dest wave-uniform base + lane*16 (linear)
__device__ __forceinline__ void gload_lds16(const bf16* g, bf16* l){
  __builtin_amdgcn_global_load_lds((const __attribute__((address_space(1))) void*)g,
                                   (__attribute__((address_space(3))) void*)l, 16, 0, 0);
}

// ---------------- LayerNorm: x (b,n,512) fp32 -> xn bf16 ----------------
__global__ __launch_bounds__(256) void k_layernorm(const float* __restrict__ x,
    const float* __restrict__ gamma, const float* __restrict__ beta,
    bf16* __restrict__ xn){
  int row = blockIdx.x;
  const float* xr = x + (size_t)row * D_;
  bf16* o = xn + (size_t)row * D_;
  int t = threadIdx.x;
  float v0 = xr[t], v1 = xr[t+256];
  float s = v0+v1, ss = v0*v0 + v1*v1;
  __shared__ float sh[8];
  for (int off=32; off; off>>=1){ s += __shfl_xor(s,off); ss += __shfl_xor(ss,off); }
  int lane = t&63, wid = t>>6;
  if (lane==0){ sh[wid] = s; sh[wid+4] = ss; }
  __syncthreads();
  float S  = sh[0]+sh[1]+sh[2]+sh[3];
  float SS = sh[4]+sh[5]+sh[6]+sh[7];
  float mu = S*(1.f/D_);
  float var = SS*(1.f/D_) - mu*mu;
  float rs = rsqrtf(var + 1e-5f);
  o[t]     = f2bf((v0-mu)*rs*gamma[t]     + beta[t]);
  o[t+256] = f2bf((v1-mu)*rs*gamma[t+256] + beta[t+256]);
}

// ---------------- W transpose+convert, both weights in ONE launch ----------------
__global__ __launch_bounds__(256) void k_wt2(const float* __restrict__ W1, bf16* __restrict__ WT1,
    const float* __restrict__ W2, bf16* __restrict__ WT2o){
  int bx = blockIdx.x;
  const float* W; bf16* WT; int C, cx;
  if (bx < 24){ W = W1; WT = WT1; C = 1536; cx = bx; }
  else        { W = W2; WT = WT2o; C = 512;  cx = bx - 24; }
  int c0 = cx*64, r0 = blockIdx.y*64;
  __shared__ float tile[64][65];
  int t = threadIdx.x;
  for (int i=t;i<4096;i+=256){ int r=i>>6, c=i&63; tile[r][c] = W[(size_t)(r0+r)*C + c0+c]; }
  __syncthreads();
  for (int i=t;i<512;i+=256){
    int c=i>>3, rg=i&7;
    short8 o;
    #pragma unroll
    for (int j=0;j<8;j++) ((bf16*)&o)[j] = f2bf(tile[rg*8+j][c]);
    *(short8*)&WT[(size_t)(c0+c)*512 + r0 + rg*8] = o;
  }
}

// ---------------- QKV GEMM: global_load_lds + both-sides XOR swizzle (rule 21c) ----------------
// Linear LDS [128][64]; swizzle phys_colE = colE ^ ((row&7)*8). Write side: lane L sources
// global chunk ((L&7)^(L>>3)) so the linear gload_lds lands content pre-swizzled; read side
// XORs the same pattern -> conflict-free. 128x256 tile, LDS-transposed full-line epilogue,
// fused landmark + vT (pass-B).
__global__ __launch_bounds__(256, 2) void k_mm_qkv4(const bf16* __restrict__ A, const bf16* __restrict__ WT,
    bf16* __restrict__ qbuf, bf16* __restrict__ kbuf, bf16* __restrict__ vbuf,
    bf16* __restrict__ vT, bf16* __restrict__ qlb, bf16* __restrict__ klb){
  __shared__ __align__(16) bf16 smem[3*128*64];
  bf16 (*As)[64]  = (bf16(*)[64])smem;
  bf16 (*Bs0)[64] = (bf16(*)[64])(smem + 128*64);
  bf16 (*Bs1)[64] = (bf16(*)[64])(smem + 2*128*64);
  bf16 (*ebuf)[136] = (bf16(*)[136])smem;   // epilogue reuse (34816 elems <= 49152)
  int t = threadIdx.x;
  int w = t>>6, lane = t&63, qd = lane>>4, n = lane&15;
  int wm = w>>1, wn = w&1;
  int r0 = blockIdx.y*128, c0 = blockIdx.x*256;
  int lrow = w*8 + (lane>>3);              // staging row within each 32-row chunk
  int csw  = ((lane&7) ^ (lane>>3)) * 8;   // inverse-swizzled source chunk (elements)
  int xA = (n&7)*8;                        // read-side XOR (row&7 == n&7 for frag rows)
  f32x4 acc[2][4][4];
  #pragma unroll
  for (int cb=0;cb<2;cb++)
    #pragma unroll
    for (int i=0;i<4;i++)
      #pragma unroll
      for (int j=0;j<4;j++) acc[cb][i][j] = (f32x4){0.f,0.f,0.f,0.f};
  for (int k0=0; k0<512; k0+=64){
    #pragma unroll
    for (int ch=0; ch<4; ch++){
      int m = ch*32 + lrow;
      gload_lds16(&A [(size_t)(r0+m)*512 + k0 + csw], &As[ch*32 + w*8][0]);
      gload_lds16(&WT[(size_t)(c0+m)*512 + k0 + csw], &Bs0[ch*32 + w*8][0]);
      gload_lds16(&WT[(size_t)(c0+128+m)*512 + k0 + csw], &Bs1[ch*32 + w*8][0]);
    }
    __syncthreads();
    #pragma unroll
    for (int ksub=0; ksub<2; ksub++){
      int colE = (ksub*32 + qd*8) ^ xA;
      short8 af[4];
      #pragma unroll
      for (int i=0;i<4;i++) af[i] = *(const short8*)&As[wm*64+i*16+n][colE];
      #pragma unroll
      for (int cb=0; cb<2; cb++){
        bf16 (*Bsc)[64] = cb ? Bs1 : Bs0;
        short8 bfr[4];
        #pragma unroll
        for (int j=0;j<4;j++) bfr[j] = *(const short8*)&Bsc[wn*64+j*16+n][colE];
        #pragma unroll
        for (int i=0;i<4;i++)
          #pragma unroll
          for (int j=0;j<4;j++) acc[cb][i][j] = mfma16(af[i], bfr[j], acc[cb][i][j]);
      }
    }
    __syncthreads();
  }
  int part = c0 >> 9;   // uniform per block
  bf16* dst = (part==0)? qbuf : (part==1)? kbuf : vbuf;
  float scale = (part==0)? 0.125f : 1.f;
  int b = r0 >> 13, nn = r0 & 8191;
  #pragma unroll
  for (int cb=0; cb<2; cb++){
    __syncthreads();
    #pragma unroll
    for (int i=0;i<4;i++)
      #pragma unroll
      for (int j=0;j<4;j++)
        #pragma unroll
        for (int rg=0; rg<4; rg++)
          ebuf[wm*64+i*16+qd*4+rg][wn*64+j*16+n] = f2bf(acc[cb][i][j][rg]*scale);
    __syncthreads();
    #pragma unroll
    for (int rep=0; rep<8; rep++){
      int unit = rep*256 + t;
      int row = unit >> 4, ch = unit & 15;
      int col = c0 + cb*128 + ch*8;
      int cc = col & 511, h = cc>>6, dh = cc&63;
      *(short8*)&dst[(((size_t)(b*H_+h))*N_ + nn + row)*DH_ + dh] = *(const short8*)&ebuf[row][ch*8];
    }
    if (part < 2){
      bf16* lt = (part==0) ? qlb : klb;
      #pragma unroll
      for (int rep=0; rep<2; rep++){
        int oi = rep*256 + t;          // 0..511: chunk(4) x col(128)
        int chunk = oi >> 7, col = oi & 127;
        float sum = 0.f;
        #pragma unroll
        for (int rr=0; rr<32; rr++) sum += bf2f(ebuf[chunk*32+rr][col]);
        int m = (nn >> 5) + chunk;
        int cc = (c0 + cb*128 + col) & 511;
        int h = cc >> 6, dh = cc & 63;
        lt[(((size_t)(b*H_+h))*M_ + m)*DH_ + dh] = f2bf(sum * (1.f/LCH));
      }
    } else {
      // pass B: refill ebuf TRANSPOSED from acc; 8B ds_writes, then full-line vT stores.
      __syncthreads();
      #pragma unroll
      for (int i=0;i<4;i++)
        #pragma unroll
        for (int j=0;j<4;j++){
          short4v tv;
          #pragma unroll
          for (int rg=0; rg<4; rg++) ((bf16*)&tv)[rg] = f2bf(acc[cb][i][j][rg]);
          *(short4v*)&ebuf[wn*64+j*16+n][wm*64+i*16+qd*4] = tv;
        }
      __syncthreads();
      #pragma unroll
      for (int rep=0; rep<8; rep++){
        int unit = rep*256 + t;        // col(128) x ch(16)
        int col = unit >> 4, ch = unit & 15;
        int cc = (c0 + cb*128 + col) & 511;
        int h = cc >> 6, dh = cc & 63;
        *(short8*)&vT[(((size_t)(b*H_+h))*DH_ + dh)*N_ + nn + ch*8] = *(const short8*)&ebuf[col][ch*8];
      }
    }
  }
}

// ---------------- attn2 = softmax(q_l @ k_l^T), no-max ----------------
__global__ __launch_bounds__(256) void k_attn2(const bf16* __restrict__ ql, const bf16* __restrict__ kl,
    float* __restrict__ A2, bf16* __restrict__ A2b){
  int bhm = blockIdx.x;
  int bh = bhm >> 8, m = bhm & 255;
  int t = threadIdx.x;
  __shared__ float qrow[64];
  __shared__ float sh[4];
  if (t < 64) qrow[t] = bf2f(ql[((size_t)bh*M_ + m)*DH_ + t]);
  __syncthreads();
  const bf16* krow = kl + ((size_t)bh*M_ + t)*DH_;
  float s = 0.f;
  #pragma unroll
  for (int i=0;i<64;i++) s += qrow[i]*bf2f(krow[i]);
  float e = __expf(s);
  float sum = e;
  for (int off=32; off; off>>=1) sum += __shfl_xor(sum, off);
  if ((t&63)==0) sh[t>>6] = sum;
  __syncthreads();
  sum = sh[0]+sh[1]+sh[2]+sh[3];
  float r = e/sum;
  A2[((size_t)bh*M_ + m)*M_ + t] = r;
  A2b[((size_t)bh*M_ + m)*M_ + t] = f2bf(r);
}

// ---------------- pinv init: Z = A^T / max_colsum (softmax rows sum to 1) ----------------
__global__ __launch_bounds__(256) void k_pinv_init(const float* __restrict__ A2, bf16* __restrict__ Z){
  int bh = blockIdx.x;
  int t = threadIdx.x;
  const float* Ab = A2 + (size_t)bh*M_*M_;
  bf16* Zb = Z + (size_t)bh*M_*M_;
  float cs=0.f;
  for (int r=0;r<M_;r++) cs += Ab[(size_t)r*M_ + t];
  __shared__ float sh[4];
  float v = cs;
  for (int off=32; off; off>>=1) v = fmaxf(v, __shfl_xor(v, off));
  if ((t&63)==0) sh[t>>6] = v;
  __syncthreads();
  float maxc = fmaxf(fmaxf(sh[0],sh[1]), fmaxf(sh[2],sh[3]));
  float inv = 1.f/maxc;
  for (int r=0;r<M_;r++) Zb[(size_t)r*M_ + t] = f2bf(Ab[(size_t)t*M_ + r]*inv);
}

// ---------------- pinv GEMM, pure bf16, K in 2 chunks of 128 ----------------
__global__ __launch_bounds__(256) void k_gemm_pmb(bf16* __restrict__ C, const bf16* __restrict__ A,
    const bf16* __restrict__ Bm, float bDiag, int bNeg, float cDiag, int cNeg, float cScale){
  int bh = blockIdx.y;
  int tm = blockIdx.x >> 2, tn = blockIdx.x & 3;
  const bf16* Ab = A  + (size_t)bh*65536;
  const bf16* Bb = Bm + (size_t)bh*65536;
  bf16* Cb = C + (size_t)bh*65536;
  __shared__ __align__(16) bf16 Ah[64][136];
  __shared__ __align__(16) bf16 Bh[64][136];
  int t = threadIdx.x;
  int w = t>>6, lane = t&63, qd = lane>>4, n = lane&15;
  int wm = w>>1, wn = w&1;
  int r0 = tm*64, c0 = tn*64;
  f32x4 acc[2][2];
  #pragma unroll
  for (int i=0;i<2;i++)
    #pragma unroll
    for (int j=0;j<2;j++) acc[i][j] = (f32x4){0.f,0.f,0.f,0.f};
  int arow = t>>2, akc = (t&3)*32;
  int bkrow = t>>1, bcc = (t&1)*32;
  for (int k0=0; k0<256; k0+=128){
    #pragma unroll
    for (int vv=0; vv<4; vv++)
      *(short8*)&Ah[arow][akc+vv*8] = *(const short8*)&Ab[(size_t)(r0+arow)*256 + k0+akc+vv*8];
    int kr = k0 + bkrow;
    #pragma unroll
    for (int vv=0; vv<4; vv++){
      short8 vb = *(const short8*)&Bb[(size_t)kr*256 + c0 + bcc + vv*8];
      if (bNeg){
        #pragma unroll
        for (int j=0;j<8;j++){
          float x = (kr == (c0 + bcc + vv*8 + j) ? bDiag : 0.f) - bf2f(((bf16*)&vb)[j]);
          Bh[bcc+vv*8+j][bkrow] = f2bf(x);
        }
      } else {
        #pragma unroll
        for (int j=0;j<8;j++) Bh[bcc+vv*8+j][bkrow] = ((bf16*)&vb)[j];
      }
    }
    __syncthreads();
    #pragma unroll
    for (int ksub=0; ksub<4; ksub++){
      short8 afh[2], bfh[2];
      #pragma unroll
      for (int i=0;i<2;i++) afh[i] = *(const short8*)&Ah[wm*32+i*16+n][ksub*32+qd*8];
      #pragma unroll
      for (int j=0;j<2;j++) bfh[j] = *(const short8*)&Bh[wn*32+j*16+n][ksub*32+qd*8];
      #pragma unroll
      for (int i=0;i<2;i++)
        #pragma unroll
        for (int j=0;j<2;j++) acc[i][j] = mfma16(afh[i], bfh[j], acc[i][j]);
    }
    __syncthreads();
  }
  #pragma unroll
  for (int i=0;i<2;i++){
    #pragma unroll
    for (int j=0;j<2;j++){
      int cidx = c0 + wn*32 + j*16 + n;
      #pragma unroll
      for (int rg=0; rg<4; rg++){
        int r = r0 + wm*32 + i*16 + qd*4 + rg;
        float r_ = acc[i][j][rg];
        if (cNeg) r_ = ((r==cidx)? cDiag : 0.f) - r_;
        Cb[(size_t)r*256 + cidx] = f2bf(r_*cScale);
      }
    }
  }
}

// ---------------- pinv GEMM fp32 (split precision; aBf/bBf: operand is bf16, lo=0) ----------------
// NOTE (round 4): do NOT fuse via cooperative grid.sync — device-scope fences defeat
// cross-XCD cache reuse (560MB HBM refetch, 23x slower). Small launches win.
__global__ __launch_bounds__(256) void k_gemm_pm(float* __restrict__ C, const void* __restrict__ Av,
    const void* __restrict__ Bv, float bDiag, int bNeg, float cDiag, int cNeg, float cScale,
    int aBf, int bBf){
  int bh = blockIdx.y;
  int tm = blockIdx.x >> 2, tn = blockIdx.x & 3;
  const float* Af = (const float*)Av; const bf16* A16 = (const bf16*)Av;
  const float* Bf = (const float*)Bv; const bf16* B16 = (const bf16*)Bv;
  float* Cb = C + (size_t)bh*65536;
  __shared__ __align__(16) bf16 Ah[64][72];
  __shared__ __align__(16) bf16 Al[64][72];
  __shared__ __align__(16) bf16 Bh[64][72];
  __shared__ __align__(16) bf16 Bl[64][72];
  int t = threadIdx.x;
  int w = t>>6, lane = t&63, qd = lane>>4, n = lane&15;
  int wm = w>>1, wn = w&1;
  int r0 = tm*64, c0 = tn*64;
  f32x4 acc[2][2];
  #pragma unroll
  for (int i=0;i<2;i++)
    #pragma unroll
    for (int j=0;j<2;j++) acc[i][j] = (f32x4){0.f,0.f,0.f,0.f};
  int srow = t>>3, skc = t&7;
  for (int k0=0; k0<256; k0+=64){
    #pragma unroll
    for (int ch=0; ch<2; ch++){
      int m = ch*32 + srow;
      if (aBf){
        *(short8*)&Ah[m][skc*8] = *(const short8*)&A16[(size_t)bh*65536 + (size_t)(r0+m)*256 + k0 + skc*8];
      } else {
        short8 vh, vl;
        const float* ap = &Af[(size_t)bh*65536 + (size_t)(r0+m)*256 + k0 + skc*8];
        #pragma unroll
        for (int j=0;j<8;j++){
          float x = ap[j];
          bf16 h = f2bf(x);
          ((bf16*)&vh)[j] = h;
          ((bf16*)&vl)[j] = f2bf(x - bf2f(h));
        }
        *(short8*)&Ah[m][skc*8] = vh;
        *(short8*)&Al[m][skc*8] = vl;
      }
      int kr = k0 + m;
      if (bBf){
        short8 vb = *(const short8*)&B16[(size_t)bh*65536 + (size_t)(k0+m)*256 + c0 + skc*8];
        #pragma unroll
        for (int j=0;j<8;j++) Bh[skc*8+j][m] = ((bf16*)&vb)[j];
      } else {
        const float* bp = &Bf[(size_t)bh*65536 + (size_t)(k0+m)*256 + c0 + skc*8];
        #pragma unroll
        for (int j=0;j<8;j++){
          float x = bp[j];
          if (bNeg) x = (kr == (c0 + skc*8 + j) ? bDiag : 0.f) - x;
          bf16 h = f2bf(x);
          Bh[skc*8+j][m] = h;
          Bl[skc*8+j][m] = f2bf(x - bf2f(h));
        }
      }
    }
    __syncthreads();
    #pragma unroll
    for (int ksub=0; ksub<2; ksub++){
      short8 afh[2], afl[2], bfh[2], bfl[2];
      #pragma unroll
      for (int i=0;i<2;i++){
        afh[i] = *(const short8*)&Ah[wm*32+i*16+n][ksub*32+qd*8];
        if (!aBf) afl[i] = *(const short8*)&Al[wm*32+i*16+n][ksub*32+qd*8];
      }
      #pragma unroll
      for (int j=0;j<2;j++){
        bfh[j] = *(const short8*)&Bh[wn*32+j*16+n][ksub*32+qd*8];
        if (!bBf) bfl[j] = *(const short8*)&Bl[wn*32+j*16+n][ksub*32+qd*8];
      }
      #pragma unroll
      for (int i=0;i<2;i++)
        #pragma unroll
        for (int j=0;j<2;j++){
          if (!aBf) acc[i][j] = mfma16(afl[i], bfh[j], acc[i][j]);
          if (!bBf) acc[i][j] = mfma16(afh[i], bfl[j], acc[i][j]);
          acc[i][j] = mfma16(afh[i], bfh[j], acc[i][j]);
        }
    }
    __syncthreads();
  }
  #pragma unroll
  for (int i=0;i<2;i++){
    #pragma unroll
    for (int j=0;j<2;j++){
      int cidx = c0 + wn*32 + j*16 + n;
      #pragma unroll
      for (int rg=0; rg<4; rg++){
        int r = r0 + wm*32 + i*16 + qd*4 + rg;
        float r_ = acc[i][j][rg];
        if (cNeg) r_ = ((r==cidx)? cDiag : 0.f) - r_;
        Cb[(size_t)r*256 + cidx] = r_*cScale;
      }
    }
  }
}

// ---------------- batched GEMM 256x64x256: z2T = (Z @ kv3)^T ----------------
__global__ __launch_bounds__(256) void k_gemm_z2(bf16* __restrict__ z2t, const float* __restrict__ A,
    const bf16* __restrict__ Bm){
  int bh = blockIdx.y;
  int tm = blockIdx.x;
  const float* Ab = A  + (size_t)bh*65536;
  const bf16* Bb = Bm + (size_t)bh*M_*DH_;
  __shared__ float As[16][68];
  __shared__ float Bs[16][64];
  int t = threadIdx.x, tx = t&15, ty = t>>4;
  int r0 = tm*64;
  float acc[4][4] = {};
  for (int k0=0;k0<256;k0+=16){
    for (int i=t;i<1024;i+=256){
      int m=i>>4, kq=i&15;
      As[kq][m] = Ab[(size_t)(r0+m)*256 + k0+kq];
      int nn=i&63, k2=i>>6;
      Bs[k2][nn] = bf2f(Bb[(size_t)(k0+k2)*64 + nn]);
    }
    __syncthreads();
    #pragma unroll
    for (int kq=0;kq<16;kq++){
      float a0[4], b0[4];
      #pragma unroll
      for (int i=0;i<4;i++) a0[i] = As[kq][ty*4+i];
      #pragma unroll
      for (int j=0;j<4;j++) b0[j] = Bs[kq][tx*4+j];
      #pragma unroll
      for (int i=0;i<4;i++)
        #pragma unroll
        for (int j=0;j<4;j++) acc[i][j] += a0[i]*b0[j];
    }
    __syncthreads();
  }
  #pragma unroll
  for (int i=0;i<4;i++){
    int r = r0+ty*4+i;
    #pragma unroll
    for (int j=0;j<4;j++)
      z2t[(size_t)bh*16384 + (size_t)(tx*4+j)*256 + r] = f2bf(acc[i][j]);
  }
}

// ---------------- attn3 flash, no-max softmax ----------------
__global__ __launch_bounds__(256, 2) void k_flash_split(const bf16* __restrict__ Q,
    const bf16* __restrict__ K, const bf16* __restrict__ VT,
    float* __restrict__ OP, float* __restrict__ LP){
  int bh = blockIdx.y;
  int sp = blockIdx.x;
  int t = threadIdx.x, w = t>>6, lane = t&63, qd = lane>>4, n = lane&15;
  int r0 = w*64;
  const size_t Qoff = ((size_t)bh*M_ + r0)*DH_;
  const size_t Koff = ((size_t)bh*N_ + (size_t)sp*CS)*DH_;
  const size_t Voff = (size_t)bh*DH_*N_ + (size_t)sp*CS;
  __shared__ __align__(16) bf16 pbuf[4][4][16][72];
  short8 aq[4][2];
  #pragma unroll
  for (int rt=0; rt<4; rt++){
    aq[rt][0] = *(const short8*)&Q[Qoff + (size_t)(rt*16+n)*DH_ + qd*8];
    aq[rt][1] = *(const short8*)&Q[Qoff + (size_t)(rt*16+n)*DH_ + 32 + qd*8];
  }
  f32x4 o[4][4];
  float lrun[4][4];
  #pragma unroll
  for (int rt=0; rt<4; rt++){
    #pragma unroll
    for (int j=0;j<4;j++){ o[rt][j] = (f32x4){0.f,0.f,0.f,0.f}; lrun[rt][j] = 0.f; }
  }
  for (int tl=0; tl<CS/64; ++tl){
    const bf16* kp = K + Koff + (size_t)(tl*64)*DH_;
    short8 kb[4][2];
    #pragma unroll
    for (int cg=0; cg<4; cg++){
      kb[cg][0] = *(const short8*)&kp[(size_t)(cg*16+n)*DH_ + qd*8];
      kb[cg][1] = *(const short8*)&kp[(size_t)(cg*16+n)*DH_ + 32 + qd*8];
    }
    #pragma unroll
    for (int rt=0; rt<4; rt++){
      f32x4 s[4];
      #pragma unroll
      for (int cg=0; cg<4; cg++){
        f32x4 z = (f32x4){0.f,0.f,0.f,0.f};
        z = mfma16(aq[rt][0], kb[cg][0], z);
        z = mfma16(aq[rt][1], kb[cg][1], z);
        s[cg] = z;
      }
      #pragma unroll
      for (int rg=0; rg<4; rg++){
        float p0 = __expf(s[0][rg]), p1 = __expf(s[1][rg]);
        float p2 = __expf(s[2][rg]), p3 = __expf(s[3][rg]);
        float ts = p0+p1+p2+p3;
        ts += __shfl_xor(ts,1); ts += __shfl_xor(ts,2);
        ts += __shfl_xor(ts,4); ts += __shfl_xor(ts,8);
        lrun[rt][rg] += ts;
        pbuf[w][rt][qd*4+rg][n]    = f2bf(p0);
        pbuf[w][rt][qd*4+rg][16+n] = f2bf(p1);
        pbuf[w][rt][qd*4+rg][32+n] = f2bf(p2);
        pbuf[w][rt][qd*4+rg][48+n] = f2bf(p3);
      }
    }
    const bf16* vp = VT + Voff + tl*64 + qd*8;
    short8 vb[4][2];
    #pragma unroll
    for (int dg=0; dg<4; dg++){
      vb[dg][0] = *(const short8*)&vp[(size_t)(dg*16+n)*N_];
      vb[dg][1] = *(const short8*)&vp[(size_t)(dg*16+n)*N_ + 32];
    }
    #pragma unroll
    for (int rt=0; rt<4; rt++){
      short8 ap0 = *(const short8*)&pbuf[w][rt][n][qd*8];
      short8 ap1 = *(const short8*)&pbuf[w][rt][n][32+qd*8];
      #pragma unroll
      for (int dg=0; dg<4; dg++){
        o[rt][dg] = mfma16(ap0, vb[dg][0], o[rt][dg]);
        o[rt][dg] = mfma16(ap1, vb[dg][1], o[rt][dg]);
      }
    }
  }
  size_t base = ((size_t)sp*(B_*H_) + bh)*M_;
  #pragma unroll
  for (int rt=0; rt<4; rt++){
    #pragma unroll
    for (int rg=0; rg<4; rg++){
      int row = r0 + rt*16 + qd*4 + rg;
      if (n==0) LP[base+row] = lrun[rt][rg];
      #pragma unroll
      for (int dg=0; dg<4; dg++)
        OP[(base+row)*DH_ + dg*16 + n] = o[rt][dg][rg];
    }
  }
}

// ---------------- merge NSPLIT flash partials -> kv3 ----------------
__global__ __launch_bounds__(256) void k_flash_merge(const float* __restrict__ OP,
    const float* __restrict__ LP, bf16* __restrict__ O){
  int bh = blockIdx.y;
  int r = blockIdx.x*4 + (threadIdx.x>>6);
  int dh = threadIdx.x & 63;
  float acc = 0.f, den = 0.f;
  for (int s=0; s<NSPLIT; s++){
    size_t base = ((size_t)s*(B_*H_) + bh)*M_ + r;
    den += LP[base];
    acc += OP[base*DH_ + dh];
  }
  O[((size_t)bh*M_ + r)*DH_ + dh] = f2bf(acc/den);
}

// ---------------- attn1 flash + FUSED depthwise conv ----------------
// Block owns 256 contiguous rows of one bh. v tile [R0-16,R0+272) staged to LDS at kernel
// start (latency hidden under attention). Attn output parked in pbuf (=obuf[256][72]),
// then conv_add's loop adds the 33-tap conv and stores once (RMW eliminated).
__global__ __launch_bounds__(256, 2) void k_flash_w3(const bf16* __restrict__ Q,
    const bf16* __restrict__ K, const bf16* __restrict__ VT,
    const bf16* __restrict__ v, const float* __restrict__ wconv, bf16* __restrict__ O){
  int bh = blockIdx.y;
  int t = threadIdx.x, w = t>>6, lane = t&63, qd = lane>>4, n = lane&15;
  int R0 = blockIdx.x*256;
  int r0 = R0 + w*64;
  int h = bh & 7;
  const size_t Qoff = ((size_t)bh*N_ + r0)*DH_;
  const size_t Koff = (size_t)bh*M_*DH_;
  const size_t Voff = (size_t)bh*DH_*M_;
  __shared__ __align__(16) bf16 pbuf[4][4][16][72];   // 36864 elems; reused as obuf[256][72]
  __shared__ __align__(16) bf16 vtile[288][72];
  __shared__ float wk[KER_];
  if (t < KER_) wk[t] = wconv[h*KER_ + t];
  // stage v halo tile early; consumed only after the final __syncthreads
  {
    const bf16* vb = v + (size_t)bh*N_*DH_;
    for (int i=t; i<288*8; i+=256){
      int r = i>>3, cg = i&7;
      int nn = R0 - 16 + r;
      short8 val = {0,0,0,0,0,0,0,0};
      if (nn >= 0 && nn < N_) val = *(const short8*)&vb[(size_t)nn*DH_ + cg*8];
      *(short8*)&vtile[r][cg*8] = val;
    }
  }
  short8 aq[4][2];
  #pragma unroll
  for (int rt=0; rt<4; rt++){
    aq[rt][0] = *(const short8*)&Q[Qoff + (size_t)(rt*16+n)*DH_ + qd*8];
    aq[rt][1] = *(const short8*)&Q[Qoff + (size_t)(rt*16+n)*DH_ + 32 + qd*8];
  }
  f32x4 o[4][4];
  float lrun[4][4];
  #pragma unroll
  for (int rt=0; rt<4; rt++){
    #pragma unroll
    for (int j=0;j<4;j++){ o[rt][j] = (f32x4){0.f,0.f,0.f,0.f}; lrun[rt][j] = 0.f; }
  }
  #pragma unroll
  for (int tl=0; tl<4; ++tl){
    const bf16* kp = K + Koff + (size_t)(tl*64)*DH_;
    short8 kb[4][2];
    #pragma unroll
    for (int cg=0; cg<4; cg++){
      kb[cg][0] = *(const short8*)&kp[(size_t)(cg*16+n)*DH_ + qd*8];
      kb[cg][1] = *(const short8*)&kp[(size_t)(cg*16+n)*DH_ + 32 + qd*8];
    }
    #pragma unroll
    for (int rt=0; rt<4; rt++){
      f32x4 s[4];
      #pragma unroll
      for (int cg=0; cg<4; cg++){
        f32x4 z = (f32x4){0.f,0.f,0.f,0.f};
        z = mfma16(aq[rt][0], kb[cg][0], z);
        z = mfma16(aq[rt][1], kb[cg][1], z);
        s[cg] = z;
      }
      #pragma unroll
      for (int rg=0; rg<4; rg++){
        float p0 = __expf(s[0][rg]), p1 = __expf(s[1][rg]);
        float p2 = __expf(s[2][rg]), p3 = __expf(s[3][rg]);
        float ts = p0+p1+p2+p3;
        ts += __shfl_xor(ts,1); ts += __shfl_xor(ts,2);
        ts += __shfl_xor(ts,4); ts += __shfl_xor(ts,8);
        lrun[rt][rg] += ts;
        pbuf[w][rt][qd*4+rg][n]    = f2bf(p0);
        pbuf[w][rt][qd*4+rg][16+n] = f2bf(p1);
        pbuf[w][rt][qd*4+rg][32+n] = f2bf(p2);
        pbuf[w][rt][qd*4+rg][48+n] = f2bf(p3);
      }
    }
    const bf16* vp = VT + Voff + tl*64 + qd*8;
    short8 vb[4][2];
    #pragma unroll
    for (int dg=0; dg<4; dg++){
      vb[dg][0] = *(const short8*)&vp[(size_t)(dg*16+n)*M_];
      vb[dg][1] = *(const short8*)&vp[(size_t)(dg*16+n)*M_ + 32];
    }
    #pragma unroll
    for (int rt=0; rt<4; rt++){
      short8 ap0 = *(const short8*)&pbuf[w][rt][n][qd*8];
      short8 ap1 = *(const short8*)&pbuf[w][rt][n][32+qd*8];
      #pragma unroll
      for (int dg=0; dg<4; dg++){
        o[rt][dg] = mfma16(ap0, vb[dg][0], o[rt][dg]);
        o[rt][dg] = mfma16(ap1, vb[dg][1], o[rt][dg]);
      }
    }
  }
  // park normalized attn output in pbuf-as-obuf[256][72] (wave writes only its quarter)
  bf16 (*obuf)[72] = (bf16(*)[72])pbuf;
  #pragma unroll
  for (int rt=0; rt<4; rt++){
    #pragma unroll
    for (int rg=0; rg<4; rg++){
      float inv = 1.f/lrun[rt][rg];
      int row = w*64 + rt*16 + qd*4 + rg;
      #pragma unroll
      for (int dg=0; dg<4; dg++)
        obuf[row][dg*16 + n] = f2bf(o[rt][dg][rg]*inv);
    }
  }
  __syncthreads();
  // conv + add + single store
  int dhg = t & 7, rowg = t >> 3;
  bf16* ob = O + ((size_t)bh*N_ + R0)*DH_;
  #pragma unroll
  for (int rr=0; rr<8; rr++){
    int lr = rowg*8 + rr;
    float acc[8] = {0.f,0.f,0.f,0.f,0.f,0.f,0.f,0.f};
    #pragma unroll 3
    for (int tt=0; tt<KER_; tt++){
      short8 vv = *(const short8*)&vtile[lr+tt][dhg*8];
      float wt = wk[tt];
      #pragma unroll
      for (int j=0;j<8;j++) acc[j] += wt * bf2f(((bf16*)&vv)[j]);
    }
    short8 ao = *(const short8*)&obuf[lr][dhg*8];
    short8 oo;
    #pragma unroll
    for (int j=0;j<8;j++) ((bf16*)&oo)[j] = f2bf(bf2f(((bf16*)&ao)[j]) + acc[j]);
    *(short8*)&ob[(size_t)lr*DH_ + dhg*8] = oo;
  }
}

// ---------------- final GEMM: out = x + gather(outh) @ WT2^T + b_out ----------------
__global__ __launch_bounds__(256) void k_mm_out2(const bf16* __restrict__ Ahd, const bf16* __restrict__ WT2,
    const float* __restrict__ bias, const float* __restrict__ xin, float* __restrict__ out){
  __shared__ __align__(16) bf16 As[128][72];
  __shared__ __align__(16) bf16 Bs[128][72];
  int t = threadIdx.x;
  int w = t>>6, lane = t&63, qd = lane>>4, n = lane&15;
  int wm = w>>1, wn = w&1;
  int bid = blockIdx.x;                // 0..1023
  int xcd = bid & 7, pos = bid >> 3;
  int tid = xcd*128 + pos;
  int cx = tid & 3, ry = tid >> 2;
  int r0 = ry*128, c0 = cx*128;
  f32x4 acc[4][4];
  #pragma unroll
  for (int i=0;i<4;i++)
    #pragma unroll
    for (int j=0;j<4;j++) acc[i][j] = (f32x4){0.f,0.f,0.f,0.f};
  int srow = t>>3, skc = t&7;
  for (int k0=0; k0<512; k0+=64){
    int h = k0 >> 6;
    #pragma unroll
    for (int ch=0; ch<4; ch++){
      int m = ch*32 + srow;
      int r = r0 + m, b = r>>13, nn = r&8191;
      *(short8*)&As[m][skc*8] = *(const short8*)&Ahd[((size_t)(b*H_+h)*N_ + nn)*DH_ + skc*8];
      *(short8*)&Bs[m][skc*8] = *(const short8*)&WT2[(size_t)(c0+m)*512 + k0 + skc*8];
    }
    __syncthreads();
    #pragma unroll
    for (int ksub=0; ksub<2; ksub++){
      short8 af[4], bfr[4];
      #pragma unroll
      for (int i=0;i<4;i++) af[i]  = *(const short8*)&As[wm*64+i*16+n][ksub*32+qd*8];
      #pragma unroll
      for (int j=0;j<4;j++) bfr[j] = *(const short8*)&Bs[wn*64+j*16+n][ksub*32+qd*8];
      #pragma unroll
      for (int i=0;i<4;i++)
        #pragma unroll
        for (int j=0;j<4;j++) acc[i][j] = mfma16(af[i], bfr[j], acc[i][j]);
    }
    __syncthreads();
  }
  #pragma unroll
  for (int i=0;i<4;i++){
    #pragma unroll
    for (int rg=0; rg<4; rg++){
      int r = r0 + wm*64 + i*16 + qd*4 + rg;
      size_t base = (size_t)r*512;
      #pragma unroll
      for (int j=0;j<4;j++){
        int c = c0 + wn*64 + j*16 + n;
        out[base + c] = acc[i][j][rg] + bias[c] + xin[base + c];
      }
    }
  }
}

extern "C" void kernel_launch(void* const* d_in, const int* in_sizes, int n_in,
                              void* d_out, int out_size, void* d_ws, size_t ws_size,
                              hipStream_t stream) {
  const float* x     = (const float*)d_in[0];
  const float* gamma = (const float*)d_in[1];
  const float* beta  = (const float*)d_in[2];
  const float* wqkv  = (const float*)d_in[3];
  const float* resk  = (const float*)d_in[4];
  const float* wout  = (const float*)d_in[5];
  const float* bout  = (const float*)d_in[6];
  float* out = (float*)d_out;

  const size_t SL = (size_t)B_*H_*N_*DH_;
  const size_t SM = (size_t)B_*H_*M_*DH_;
  const size_t SP = (size_t)B_*H_*M_*M_;

  bf16* xn  = (bf16*)d_ws;
  bf16* q   = xn + SL;
  bf16* k   = q + SL;          // k region dead after flash_split -> bf16 pinv scratch
  bf16* v   = k + SL;
  bf16* vT  = v + SL;
  bf16* ql  = vT + SL;
  bf16* kl  = ql + SM;
  bf16* kv3 = kl + SM;
  bf16* z2T = kv3 + SM;
  float* A2 = (float*)(z2T + SM);
  bf16* WT  = (bf16*)(A2 + SP);
  bf16* WT2 = WT + (size_t)1536*512;
  float* P1 = (float*)xn;
  float* P2 = P1 + SP;
  float* P3 = P2 + SP;
  float* P4 = P3 + SP;
  float* OPp = (float*)xn;
  float* LPp = (float*)z2T;
  bf16* A2b = k;
  bf16* Zb0 = A2b + SP;
  bf16* Zb1 = Zb0 + SP;
  bf16* Pb  = Zb1 + SP;
  bf16* Tb  = Pb + SP;
  bf16* Ub  = Tb + SP;

  k_wt2<<<dim3(32, 8), 256, 0, stream>>>(wqkv, WT, wout, WT2);
  k_layernorm<<<B_*N_, 256, 0, stream>>>(x, gamma, beta, xn);
  k_mm_qkv4<<<dim3(6, 256), 256, 0, stream>>>(xn, WT, q, k, v, vT, ql, kl);

  k_flash_split<<<dim3(NSPLIT, B_*H_), 256, 0, stream>>>(ql, k, vT, OPp, LPp);
  k_flash_merge<<<dim3(M_/4, B_*H_), 256, 0, stream>>>(OPp, LPp, kv3);

  k_attn2<<<B_*H_*M_, 256, 0, stream>>>(ql, kl, A2, A2b);
  k_pinv_init<<<B_*H_, 256, 0, stream>>>(A2, Zb0);

  bf16* Zbi = Zb0; bf16* Zbo = Zb1;
  for (int it=0; it<5; ++it){
    k_gemm_pmb<<<dim3(16,32), 256, 0, stream>>>(Pb,  A2b, Zbi, 0.f,0, 0.f,0, 1.f);
    k_gemm_pmb<<<dim3(16,32), 256, 0, stream>>>(Tb,  Pb,  Pb,  7.f,1, 15.f,1, 1.f);
    k_gemm_pmb<<<dim3(16,32), 256, 0, stream>>>(Ub,  Pb,  Tb,  0.f,0, 13.f,1, 1.f);
    k_gemm_pmb<<<dim3(16,32), 256, 0, stream>>>(Zbo, Zbi, Ub,  0.f,0, 0.f,0, 0.25f);
    bf16* tt = Zbi; Zbi = Zbo; Zbo = tt;
  }
  k_gemm_pm<<<dim3(16,32), 256, 0, stream>>>(P2, A2, Zbi, 0.f,0, 0.f,0, 1.f,  0,1);
  k_gemm_pm<<<dim3(16,32), 256, 0, stream>>>(P3, P2, P2,  7.f,1, 15.f,1, 1.f, 0,0);
  k_gemm_pm<<<dim3(16,32), 256, 0, stream>>>(P4, P2, P3,  0.f,0, 13.f,1, 1.f, 0,0);
  k_gemm_pm<<<dim3(16,32), 256, 0, stream>>>(P1, Zbi, P4, 0.f,0, 0.f,0, 0.25f,1,0);

  k_gemm_z2<<<dim3(4, B_*H_), 256, 0, stream>>>(z2T, P1, kv3);
  k_flash_w3<<<dim3(N_/256, B_*H_), 256, 0, stream>>>(q, kl, z2T, v, resk, xn);
  k_mm_out2<<<1024, 256, 0, stream>>>(xn, WT2, bout, x, out);
}